// Round 7
// baseline (5244.123 us; speedup 1.0000x reference)
//
#include <hip/hip_runtime.h>
#include <math.h>

#define NN 100000
#define NE 1600000
#define NG 1000
#define IN_DIM 64
#define HID 128
#define EXD 32
#define OUTD 10
#define BN_EPS 1e-5f

#define SCAN_B 256
#define NBLK ((NN + SCAN_B - 1) / SCAN_B)   // 391

// XCD-partitioned edge placement (scattered csr writes stay XCD-local)
#define FCH 128
#define FCE (NE / FCH)          // 12500 edges per chunk
#define PR  ((NN + 7) / 8)      // 12500 nodes per part

#define AGB 12500               // gather blocks (8 nodes each, exact)
#define SRB 1024                // stats-reduce tail blocks (appended to gather grid)
#define SRC_CH ((AGB + SRB - 1) / SRB)   // 13 partial rows per block

#define GB2K ((NN + 127) / 128)          // 782 GEMM row-blocks

// mega1 grid layout: degpos(1024 edges/block) | mgemm2 | wprep | gstart
// roles INTERLEAVED via stride permutation; deg blocks carry 4 edges/thread.
#define MEGA_DEG ((NE + 1023) / 1024)    // 1563
#define MEGA_MG2 GB2K                    // 782
#define MEGA_WP  512                     // 8 matrices x 64
#define MEGA_GST NBLK                    // 391
#define MEGA_TOT (MEGA_DEG + MEGA_MG2 + MEGA_WP + MEGA_GST)   // 3248
#define MEGA_STRIDE 1023u                // gcd(1023, 3248) = 1 -> bijective

#define FILL_B (FCH * 8)                 // 1024

typedef __attribute__((ext_vector_type(8))) short bf16x8;
typedef __attribute__((ext_vector_type(4))) float f32x4;

__device__ __forceinline__ float bf2f(unsigned short h) {
    return __uint_as_float((unsigned int)h << 16);
}
__device__ __forceinline__ unsigned short f2bf(float f) {
    unsigned int u = __float_as_uint(f);
    u += 0x7fffu + ((u >> 16) & 1u);        // round to nearest even
    return (unsigned short)(u >> 16);
}

struct WPack {
    const float* w[10];
    int K[10];
};

#define CS_STRIDE 136
#define LW_STRIDE 1032          // shorts per k-chunk (1024 data + 8 pad)

// ---------------- mega1: degpos atomics || layer-1 dual GEMM || wprep || gstart ----------------
__launch_bounds__(256, 2)
__global__ void mega1_kernel(const int* __restrict__ src, const int* __restrict__ dst,
                             int* __restrict__ deg, unsigned char* __restrict__ epos,
                             const int* __restrict__ batch, int* __restrict__ gstart,
                             const float* __restrict__ x,
                             const float* __restrict__ W1raw, const float* __restrict__ Wpraw,
                             WPack wp, unsigned short* __restrict__ wf,
                             unsigned short* __restrict__ t0, unsigned short* __restrict__ t1) {
    __shared__ unsigned short sm[128 * CS_STRIDE];
    unsigned b = (unsigned)(((unsigned long long)blockIdx.x * MEGA_STRIDE) % MEGA_TOT);
    int tid = threadIdx.x;

    if (b < MEGA_DEG) {
        // 1024 edges/block, 4 independent atomics in flight per thread
        int e0 = b * 1024 + tid;
#pragma unroll
        for (int j = 0; j < 4; ++j) {
            int e = e0 + (j << 8);
            if (e < NE) epos[e] = (unsigned char)atomicAdd(&deg[dst[e]], 1);
        }
        return;
    }
    if (b < MEGA_DEG + MEGA_MG2) {
        // dual GEMM: t0 = bf16(x @ W1), t1 = bf16(x @ s1_Wp); A read as f32,
        // converted in-register. W formatted in-block from raw f32.
        int bb = (int)(b - MEGA_DEG);
        int lane = tid & 63;
        int wv = tid >> 6;
        int lane15 = lane & 15;
        int q = lane >> 4;
        int m0 = bb * 128 + wv * 32;

        for (int g = tid; g < 2048; g += 256) {
            int w = g >> 10, rem = g & 1023;
            int c = rem >> 7, n = rem & 127;
            const float* W = w ? Wpraw : W1raw;
            bf16x8 v;
#pragma unroll
            for (int j = 0; j < 8; ++j) v[j] = (short)f2bf(W[(c * 8 + j) * 128 + n]);
            *(bf16x8*)&sm[(w * 8 + c) * LW_STRIDE + n * 8] = v;
        }
        __syncthreads();

        f32x4 acc[2][2][8];
#pragma unroll
        for (int w = 0; w < 2; ++w)
#pragma unroll
            for (int r = 0; r < 2; ++r)
#pragma unroll
                for (int nt = 0; nt < 8; ++nt)
                    acc[w][r][nt] = (f32x4){0.f, 0.f, 0.f, 0.f};

        bf16x8 zf = {0, 0, 0, 0, 0, 0, 0, 0};
        int row0 = m0 + lane15;
        const float* a0p = x + (size_t)row0 * IN_DIM + (q << 3);
        const float* a1p = a0p + (size_t)16 * IN_DIM;
        bool g0 = row0 < NN, g1 = (row0 + 16) < NN;
#pragma unroll
        for (int k0 = 0; k0 < IN_DIM; k0 += 32) {
            bf16x8 af0 = zf, af1 = zf;
            if (g0) {
                float4 u0 = *(const float4*)(a0p + k0);
                float4 u1 = *(const float4*)(a0p + k0 + 4);
                af0[0] = (short)f2bf(u0.x); af0[1] = (short)f2bf(u0.y);
                af0[2] = (short)f2bf(u0.z); af0[3] = (short)f2bf(u0.w);
                af0[4] = (short)f2bf(u1.x); af0[5] = (short)f2bf(u1.y);
                af0[6] = (short)f2bf(u1.z); af0[7] = (short)f2bf(u1.w);
            }
            if (g1) {
                float4 u0 = *(const float4*)(a1p + k0);
                float4 u1 = *(const float4*)(a1p + k0 + 4);
                af1[0] = (short)f2bf(u0.x); af1[1] = (short)f2bf(u0.y);
                af1[2] = (short)f2bf(u0.z); af1[3] = (short)f2bf(u0.w);
                af1[4] = (short)f2bf(u1.x); af1[5] = (short)f2bf(u1.y);
                af1[6] = (short)f2bf(u1.z); af1[7] = (short)f2bf(u1.w);
            }
#pragma unroll
            for (int w = 0; w < 2; ++w) {
                const unsigned short* wb = &sm[(w * 8 + (k0 >> 3) + q) * LW_STRIDE + (lane15 << 3)];
#pragma unroll
                for (int nt = 0; nt < 8; ++nt) {
                    bf16x8 bf = *(const bf16x8*)(wb + nt * 128);
                    acc[w][0][nt] = __builtin_amdgcn_mfma_f32_16x16x32_bf16(af0, bf, acc[w][0][nt], 0, 0, 0);
                    acc[w][1][nt] = __builtin_amdgcn_mfma_f32_16x16x32_bf16(af1, bf, acc[w][1][nt], 0, 0, 0);
                }
            }
        }

        for (int w = 0; w < 2; ++w) {
            unsigned short* target = w ? t1 : t0;
            __syncthreads();
#pragma unroll
            for (int r = 0; r < 2; ++r)
#pragma unroll
                for (int nt = 0; nt < 8; ++nt)
#pragma unroll
                    for (int g = 0; g < 4; ++g) {
                        int rr = wv * 32 + r * 16 + q * 4 + g;
                        sm[rr * CS_STRIDE + nt * 16 + lane15] = f2bf(acc[w][r][nt][g]);
                    }
            __syncthreads();
#pragma unroll
            for (int i = 0; i < 8; ++i) {
                int rt = (tid >> 4) + i * 16;
                int ch = tid & 15;
                int row = bb * 128 + rt;
                if (row >= NN) continue;
                bf16x8 c = *(const bf16x8*)(sm + rt * CS_STRIDE + (ch << 3));
                *(bf16x8*)(target + (size_t)row * HID + (ch << 3)) = c;
            }
        }
        return;
    }
    if (b < MEGA_DEG + MEGA_MG2 + MEGA_WP) {
        int b2 = (int)(b - MEGA_DEG - MEGA_MG2);
        int m = b2 >> 6;
        int idx = ((b2 & 63) << 8) + tid;
        int K = wp.K[m];
        if (idx >= K * 128) return;
        int k = idx >> 7, n = idx & 127;
        wf[m * 16384 + (((k >> 3) * 128 + n) << 3) + (k & 7)] = f2bf(wp.w[m][idx]);
        return;
    }
    {
        int n = (int)(b - MEGA_DEG - MEGA_MG2 - MEGA_WP) * 256 + tid;
        if (n >= NN) return;
        int bc = batch[n];
        int bp = (n == 0) ? -1 : batch[n - 1];
        for (int g = bp + 1; g <= bc; ++g) gstart[g] = n;
        if (n == NN - 1)
            for (int g = bc + 1; g <= NG; ++g) gstart[g] = NN;
    }
}

// exclusive scan of deg -> rs_raw (per-block local); also dinv = rsqrt(deg+1)
// block 0 additionally zeroes the 6*128 BN-stat accumulators + 8 spin counters
__global__ void scan1_kernel(const int* __restrict__ deg, int* __restrict__ rs_raw,
                             int* __restrict__ bsums, float* __restrict__ dinv,
                             float* __restrict__ stats_out) {
    __shared__ int s[SCAN_B];
    int t = threadIdx.x;
    int i = blockIdx.x * SCAN_B + t;
    if (blockIdx.x == 0) {
        stats_out[t] = 0.f; stats_out[t + 256] = 0.f; stats_out[t + 512] = 0.f;
        if (t < 8) ((int*)stats_out)[768 + t] = 0;
    }
    int v = (i < NN) ? deg[i] : 0;
    if (i < NN) dinv[i] = rsqrtf((float)v + 1.0f);   // +1 self loop
    s[t] = v;
    __syncthreads();
    for (int off = 1; off < SCAN_B; off <<= 1) {
        int u = (t >= off) ? s[t - off] : 0;
        __syncthreads();
        s[t] += u;
        __syncthreads();
    }
    if (i < NN) rs_raw[i] = s[t] - v;
    if (t == SCAN_B - 1) bsums[blockIdx.x] = s[t];
}

// ---------------- fused: local bsums-scan + edge placement + row_start finalize ----------------
__global__ void fill_kernel(const int* __restrict__ src, const int* __restrict__ dst,
                            const int* __restrict__ rs_raw, const int* __restrict__ bsums,
                            const unsigned char* __restrict__ epos,
                            int* __restrict__ csr_src, int* __restrict__ row_fin) {
    __shared__ int sp[256];
    __shared__ int pfx[NBLK];
    int b = blockIdx.x;
    int tid = threadIdx.x;

    int b0v = (2 * tid < NBLK) ? bsums[2 * tid] : 0;
    int b1v = (2 * tid + 1 < NBLK) ? bsums[2 * tid + 1] : 0;
    sp[tid] = b0v + b1v;
    __syncthreads();
    for (int off = 1; off < 256; off <<= 1) {
        int u = (tid >= off) ? sp[tid - off] : 0;
        __syncthreads();
        sp[tid] += u;
        __syncthreads();
    }
    int excl = sp[tid] - b0v - b1v;      // sum of bsums[0 .. 2*tid-1]
    if (2 * tid < NBLK)     pfx[2 * tid]     = excl;
    if (2 * tid + 1 < NBLK) pfx[2 * tid + 1] = excl + b0v;
    __syncthreads();

    if (b < FILL_B) {
        int part = b & 7;
        int lo = part * PR, hi = min(lo + PR, NN);
        int e0 = (b >> 3) * FCE;
        for (int e = e0 + tid; e < e0 + FCE; e += 256) {
            int d = dst[e];
            if (d >= lo && d < hi)
                csr_src[rs_raw[d] + pfx[d >> 8] + (int)epos[e]] = src[e];
        }
    } else {
        int i = (b - FILL_B) * 256 + tid;
        if (i < NN) row_fin[i] = rs_raw[i] + pfx[i >> 8];
        if (i == 0) row_fin[NN] = NE;
    }
}

// ---------------- GCN aggregation: pull-gather + fused BN partial stats ----------------
// R7: gather loads reverted to R5 simple form (R6 coop-shfl was null->negative:
// wave-uniform loads were already broadcast by HW; gather is cache-BW-bound).
// NEW: stats-reduce fused as SPIN-TAIL blocks [AGB, AGB+SRB). Gather blocks
// release via per-thread __threadfence + one device-scope counter add; tail
// blocks (dispatched last, blockIdx order) acquire-spin, then reduce partials
// into gsum/gsq. Removes 3 stats dispatches + 6 launch gaps from the serial path.
__launch_bounds__(256)
__global__ void gather_kernel(const int* __restrict__ row_start,
                              const int* __restrict__ csr_src,
                              const unsigned short* __restrict__ xwb,
                              const float* __restrict__ dinv,
                              const float* __restrict__ b,
                              unsigned short* __restrict__ aggb,
                              float* __restrict__ psum, float* __restrict__ psq,
                              float* __restrict__ gsum, float* __restrict__ gsq,
                              int* __restrict__ ctr) {
    __shared__ float rsm[8][128];
    __shared__ float rqm[8][128];

    if (blockIdx.x >= AGB) {
        // ---- stats-reduce tail ----
        if (threadIdx.x == 0) {
            while (__hip_atomic_load(ctr, __ATOMIC_ACQUIRE, __HIP_MEMORY_SCOPE_AGENT) < AGB)
                __builtin_amdgcn_s_sleep(8);
        }
        __syncthreads();
        __threadfence();
        int t = threadIdx.x;
        int c = t & 127;
        bool isq = t >= 128;
        const float* p = isq ? psq : psum;
        int rb = blockIdx.x - AGB;
        int b0 = rb * SRC_CH;
        int b1 = min(b0 + SRC_CH, AGB);
        float sred = 0.f;
        for (int bi = b0; bi < b1; ++bi)
            sred += p[(size_t)bi * 128 + c];
        atomicAdd(isq ? &gsq[c] : &gsum[c], sred);
        return;
    }

    int node = blockIdx.x * 8 + (threadIdx.x >> 5);
    int lane = threadIdx.x & 31;
    int rs = row_start[node], re = row_start[node + 1];
    float d = dinv[node];
    int fo = lane << 2;
    ushort4 sv = *(const ushort4*)(xwb + (size_t)node * HID + fo);
    float4 accE = make_float4(0.f, 0.f, 0.f, 0.f);
    int e = rs;
    for (; e + 7 < re; e += 8) {
        int sI[8];
#pragma unroll
        for (int j = 0; j < 8; ++j) sI[j] = csr_src[e + j];
        float cI[8];
        ushort4 rI[8];
#pragma unroll
        for (int j = 0; j < 8; ++j) {
            cI[j] = dinv[sI[j]];
            rI[j] = *(const ushort4*)(xwb + (size_t)sI[j] * HID + fo);
        }
#pragma unroll
        for (int j = 0; j < 8; ++j) {
            accE.x += cI[j] * bf2f(rI[j].x);
            accE.y += cI[j] * bf2f(rI[j].y);
            accE.z += cI[j] * bf2f(rI[j].z);
            accE.w += cI[j] * bf2f(rI[j].w);
        }
    }
    for (; e + 1 < re; e += 2) {
        int s0 = csr_src[e], s1 = csr_src[e + 1];
        float c0 = dinv[s0], c1 = dinv[s1];
        ushort4 r0 = *(const ushort4*)(xwb + (size_t)s0 * HID + fo);
        ushort4 r1 = *(const ushort4*)(xwb + (size_t)s1 * HID + fo);
        accE.x += c0 * bf2f(r0.x) + c1 * bf2f(r1.x);
        accE.y += c0 * bf2f(r0.y) + c1 * bf2f(r1.y);
        accE.z += c0 * bf2f(r0.z) + c1 * bf2f(r1.z);
        accE.w += c0 * bf2f(r0.w) + c1 * bf2f(r1.w);
    }
    if (e < re) {
        int s0 = csr_src[e];
        float c0 = dinv[s0];
        ushort4 r0 = *(const ushort4*)(xwb + (size_t)s0 * HID + fo);
        accE.x += c0 * bf2f(r0.x);
        accE.y += c0 * bf2f(r0.y);
        accE.z += c0 * bf2f(r0.z);
        accE.w += c0 * bf2f(r0.w);
    }
    float d2 = d * d;
    ushort4 o;
    o.x = f2bf(d * accE.x + d2 * bf2f(sv.x) + b[fo + 0]);
    o.y = f2bf(d * accE.y + d2 * bf2f(sv.y) + b[fo + 1]);
    o.z = f2bf(d * accE.z + d2 * bf2f(sv.z) + b[fo + 2]);
    o.w = f2bf(d * accE.w + d2 * bf2f(sv.w) + b[fo + 3]);
    *(ushort4*)(aggb + (size_t)node * HID + fo) = o;

    // ---- fused BN partial stats (on the bf16-rounded values) ----
    float v0 = bf2f(o.x), v1 = bf2f(o.y), v2 = bf2f(o.z), v3 = bf2f(o.w);
    int sub = threadIdx.x >> 5;
    rsm[sub][fo + 0] = v0; rsm[sub][fo + 1] = v1;
    rsm[sub][fo + 2] = v2; rsm[sub][fo + 3] = v3;
    rqm[sub][fo + 0] = v0 * v0; rqm[sub][fo + 1] = v1 * v1;
    rqm[sub][fo + 2] = v2 * v2; rqm[sub][fo + 3] = v3 * v3;
    __syncthreads();
    int t = threadIdx.x;
    if (t < 128) {
        float s = 0.f, q = 0.f;
#pragma unroll
        for (int i = 0; i < 8; ++i) { s += rsm[i][t]; q += rqm[i][t]; }
        psum[(size_t)blockIdx.x * 128 + t] = s;
        psq[(size_t)blockIdx.x * 128 + t] = q;
    }
    // release: make this block's psum/psq visible, then signal
    __threadfence();
    __syncthreads();
    if (t == 0) atomicAdd(ctr, 1);
}

// ---------------- MFMA GEMM (bf16 in, f32 acc, bf16 out) ----------------
// mode 2: target = bf16(A1 @ Wa); extra blocks [GB2K, GB2K+NG) do mean-pool of A1
// mode 1: BN finalize + gated-skip epilogue
__launch_bounds__(256, 4)
__global__ void mgemm_kernel(const unsigned short* __restrict__ A1,
                             const unsigned short* __restrict__ wfA, int K1,
                             const unsigned short* A2,
                             const unsigned short* __restrict__ wfB, int K2,
                             const float* __restrict__ bias1, const float* __restrict__ bias2,
                             const unsigned short* outx,
                             const float* __restrict__ gsum, const float* __restrict__ gsq,
                             const float* __restrict__ gw, const float* __restrict__ bew,
                             unsigned short* target, int mode,
                             const int* __restrict__ gst, float* __restrict__ poolout) {
    __shared__ unsigned short sm[128 * CS_STRIDE];   // W-stage / C-stage / pool-reduce
    int tid = threadIdx.x;

    if (mode == 2 && blockIdx.x >= GB2K) {
        // fused mean-pool over A1 (reads-only overlap with the GEMM blocks)
        float* red = (float*)sm;                      // 8 x 128 floats
        int g = blockIdx.x - GB2K;
        int lane = tid & 31, sub = tid >> 5;
        int s = gst[g], e = gst[g + 1];
        float4 acc = make_float4(0.f, 0.f, 0.f, 0.f);
        for (int r = s + sub; r < e; r += 8) {
            ushort4 v = *(const ushort4*)(A1 + (size_t)r * HID + (lane << 2));
            acc.x += bf2f(v.x); acc.y += bf2f(v.y);
            acc.z += bf2f(v.z); acc.w += bf2f(v.w);
        }
        *(float4*)&red[sub * 128 + (lane << 2)] = acc;
        __syncthreads();
        if (tid < 128) {
            float a = 0.f;
#pragma unroll
            for (int i = 0; i < 8; ++i) a += red[i * 128 + tid];
            poolout[(size_t)g * HID + tid] = a / (float)max(e - s, 1);
        }
        return;
    }

    __shared__ float sclS[128], shfS[128];
    int lane = tid & 63;
    int wv = tid >> 6;
    int lane15 = lane & 15;
    int q = lane >> 4;
    int m0 = blockIdx.x * 128 + wv * 32;

    if (mode == 1 && tid < 128) {
        float mu = gsum[tid] * (1.0f / NN);
        float var = gsq[tid] * (1.0f / NN) - mu * mu;
        float sc = gw[tid] * rsqrtf(var + BN_EPS);
        sclS[tid] = sc;
        shfS[tid] = bew[tid] - mu * sc;
    }

    f32x4 acc[2][8];
#pragma unroll
    for (int r = 0; r < 2; ++r)
#pragma unroll
        for (int nt = 0; nt < 8; ++nt)
            acc[r][nt] = (f32x4){0.f, 0.f, 0.f, 0.f};

    bf16x8 zf = {0, 0, 0, 0, 0, 0, 0, 0};

    for (int p = 0; p < 2; ++p) {
        const unsigned short* A = p ? A2 : A1;
        const unsigned short* wf = p ? wfB : wfA;
        int K = p ? K2 : K1;
        if (K == 0) continue;
        bool bnA = (mode == 1) && (p == 0);
        __syncthreads();
        for (int g = tid; g < K * 16; g += 256) {
            int c = g >> 7, off = (g & 127) << 3;
            *(bf16x8*)&sm[c * LW_STRIDE + off] = *(const bf16x8*)&wf[(c << 10) + off];
        }
        __syncthreads();
        int row0 = m0 + lane15;
        const unsigned short* a0p = A + (size_t)row0 * K + (q << 3);
        const unsigned short* a1p = a0p + (size_t)16 * K;
        bool g0 = row0 < NN, g1 = (row0 + 16) < NN;
#pragma unroll 4
        for (int k0 = 0; k0 < K; k0 += 32) {
            bf16x8 af0 = zf, af1 = zf;
            if (g0) af0 = *(const bf16x8*)(a0p + k0);
            if (g1) af1 = *(const bf16x8*)(a1p + k0);
            if (bnA) {
                int kb = k0 + (q << 3);
                float4 s4a = *(const float4*)&sclS[kb];
                float4 s4b = *(const float4*)&sclS[kb + 4];
                float4 h4a = *(const float4*)&shfS[kb];
                float4 h4b = *(const float4*)&shfS[kb + 4];
                float sv[8] = {s4a.x, s4a.y, s4a.z, s4a.w, s4b.x, s4b.y, s4b.z, s4b.w};
                float hv[8] = {h4a.x, h4a.y, h4a.z, h4a.w, h4b.x, h4b.y, h4b.z, h4b.w};
#pragma unroll
                for (int j = 0; j < 8; ++j) {
                    af0[j] = (short)f2bf(fmaxf(bf2f((unsigned short)af0[j]) * sv[j] + hv[j], 0.f));
                    af1[j] = (short)f2bf(fmaxf(bf2f((unsigned short)af1[j]) * sv[j] + hv[j], 0.f));
                }
            }
            const unsigned short* wb = &sm[((k0 >> 3) + q) * LW_STRIDE + (lane15 << 3)];
#pragma unroll
            for (int nt = 0; nt < 8; ++nt) {
                bf16x8 bf = *(const bf16x8*)(wb + nt * 128);
                acc[0][nt] = __builtin_amdgcn_mfma_f32_16x16x32_bf16(af0, bf, acc[0][nt], 0, 0, 0);
                acc[1][nt] = __builtin_amdgcn_mfma_f32_16x16x32_bf16(af1, bf, acc[1][nt], 0, 0, 0);
            }
        }
    }
    __syncthreads();

    if (mode == 1) {
        float bsum[8];
#pragma unroll
        for (int nt = 0; nt < 8; ++nt)
            bsum[nt] = bias1[nt * 16 + lane15] + bias2[nt * 16 + lane15];
#pragma unroll
        for (int r = 0; r < 2; ++r)
#pragma unroll
            for (int nt = 0; nt < 8; ++nt)
#pragma unroll
                for (int g = 0; g < 4; ++g) {
                    int rr = wv * 32 + r * 16 + q * 4 + g;
                    sm[rr * CS_STRIDE + nt * 16 + lane15] = f2bf(acc[r][nt][g] + bsum[nt]);
                }
    } else {
#pragma unroll
        for (int r = 0; r < 2; ++r)
#pragma unroll
            for (int nt = 0; nt < 8; ++nt)
#pragma unroll
                for (int g = 0; g < 4; ++g) {
                    int rr = wv * 32 + r * 16 + q * 4 + g;
                    sm[rr * CS_STRIDE + nt * 16 + lane15] = f2bf(acc[r][nt][g]);
                }
    }
    __syncthreads();

#pragma unroll
    for (int i = 0; i < 8; ++i) {
        int rt = (tid >> 4) + i * 16;
        int ch = tid & 15;
        int row = blockIdx.x * 128 + rt;
        if (row >= NN) continue;
        bf16x8 c = *(const bf16x8*)(sm + rt * CS_STRIDE + (ch << 3));
        size_t off = (size_t)row * HID + (ch << 3);
        if (mode == 1) {
            int cb = ch << 3;
            float4 s4a = *(const float4*)&sclS[cb];
            float4 s4b = *(const float4*)&sclS[cb + 4];
            float4 h4a = *(const float4*)&shfS[cb];
            float4 h4b = *(const float4*)&shfS[cb + 4];
            float sv[8] = {s4a.x, s4a.y, s4a.z, s4a.w, s4b.x, s4b.y, s4b.z, s4b.w};
            float hv[8] = {h4a.x, h4a.y, h4a.z, h4a.w, h4b.x, h4b.y, h4b.z, h4b.w};
            bf16x8 oxv = *(const bf16x8*)(outx + off);
            bf16x8 ixv = *(const bf16x8*)(target + off);
            bf16x8 o;
#pragma unroll
            for (int j = 0; j < 8; ++j) {
                float t = bf2f((unsigned short)c[j]);
                float z = 1.0f / (1.0f + expf(-t));
                float ox = fmaxf(bf2f((unsigned short)oxv[j]) * sv[j] + hv[j], 0.f);
                float h = z * ox + (1.0f - z) * bf2f((unsigned short)ixv[j]);
                o[j] = (short)f2bf(h);
            }
            *(bf16x8*)(target + off) = o;
        } else {
            *(bf16x8*)(target + off) = c;
        }
    }
}

// ---------------- MLP head with fused vectorized pool3 ----------------
__global__ void head_kernel(const float* __restrict__ pool1, const float* __restrict__ pool2,
                            const unsigned short* __restrict__ h3,
                            const int* __restrict__ gstart,
                            const float* __restrict__ eF,
                            const float* __restrict__ fc1W, const float* __restrict__ fc1b,
                            const float* __restrict__ fc3W, const float* __restrict__ fc3b,
                            float* __restrict__ out) {
    __shared__ float hg[3 * HID + EXD];
    __shared__ float hh[HID];
    __shared__ float red[8][128];
    int g = blockIdx.x, t = threadIdx.x;
    int lane = t & 31, sub = t >> 5;
    int s = gstart[g], e = gstart[g + 1];
    // vectorized mean-pool of h3 (8-sub x ushort4)
    float4 acc = make_float4(0.f, 0.f, 0.f, 0.f);
    for (int r = s + sub; r < e; r += 8) {
        ushort4 v = *(const ushort4*)(h3 + (size_t)r * HID + (lane << 2));
        acc.x += bf2f(v.x); acc.y += bf2f(v.y);
        acc.z += bf2f(v.z); acc.w += bf2f(v.w);
    }
    *(float4*)&red[sub][lane << 2] = acc;
    if (t < 128) {
        hg[t]       = pool1[(size_t)g * HID + t];
        hg[HID + t] = pool2[(size_t)g * HID + t];
    } else if (t < 128 + EXD) {
        hg[3 * HID + (t - 128)] = eF[(size_t)g * EXD + (t - 128)];
    }
    __syncthreads();
    if (t < 128) {
        float a = 0.f;
#pragma unroll
        for (int i = 0; i < 8; ++i) a += red[i][t];
        hg[2 * HID + t] = a / (float)max(e - s, 1);
    }
    __syncthreads();
    if (t < 128) {
        float a = fc1b[t];
        for (int k = 0; k < 3 * HID + EXD; ++k) a += hg[k] * fc1W[(size_t)k * HID + t];
        hh[t] = fmaxf(a, 0.f);
    }
    __syncthreads();
    if (t < OUTD) {
        float a2 = fc3b[t];
        for (int k = 0; k < HID; ++k) a2 += hh[k] * fc3W[(size_t)k * OUTD + t];
        out[(size_t)g * OUTD + t] = a2;
    }
}

// ---------------- launch ----------------

extern "C" void kernel_launch(void* const* d_in, const int* in_sizes, int n_in,
                              void* d_out, int out_size, void* d_ws, size_t ws_size,
                              hipStream_t stream) {
    const float* x      = (const float*)d_in[0];
    const float* eF     = (const float*)d_in[1];
    const int*   ei     = (const int*)d_in[2];
    const int*   batch  = (const int*)d_in[3];
    const int* src = ei;
    const int* dst = ei + NE;

    const float* W1 = (const float*)d_in[4];  const float* b1 = (const float*)d_in[5];
    const float* W2 = (const float*)d_in[6];  const float* b2 = (const float*)d_in[7];
    const float* W3 = (const float*)d_in[8];  const float* b3 = (const float*)d_in[9];
    const float* g1 = (const float*)d_in[10]; const float* be1 = (const float*)d_in[11];
    const float* g2 = (const float*)d_in[12]; const float* be2 = (const float*)d_in[13];
    const float* g3 = (const float*)d_in[14]; const float* be3 = (const float*)d_in[15];
    const float* s1_Wp = (const float*)d_in[16];
    const float* s1_Wi = (const float*)d_in[17]; const float* s1_bi = (const float*)d_in[18];
    const float* s1_Wo = (const float*)d_in[19]; const float* s1_bo = (const float*)d_in[20];
    const float* s2_Wi = (const float*)d_in[21]; const float* s2_bi = (const float*)d_in[22];
    const float* s2_Wo = (const float*)d_in[23]; const float* s2_bo = (const float*)d_in[24];
    const float* s3_Wi = (const float*)d_in[25]; const float* s3_bi = (const float*)d_in[26];
    const float* s3_Wo = (const float*)d_in[27]; const float* s3_bo = (const float*)d_in[28];
    const float* fc1W = (const float*)d_in[29]; const float* fc1b = (const float*)d_in[30];
    const float* fc3W = (const float*)d_in[31]; const float* fc3b = (const float*)d_in[32];

    size_t S = (size_t)NN * HID;
    unsigned short* xwb  = (unsigned short*)d_ws;          // NN*HID
    unsigned short* xslot = xwb + S;                       // freed xb slot -> transients
    unsigned short* hb   = xslot + (size_t)NN * IN_DIM;    // NN*HID
    unsigned short* aggb = hb + S;                         // NN*HID
    unsigned short* wfb  = aggb + S;                       // 8*16384 (10 slots reserved)
    float* dinv = (float*)(wfb + 10 * 16384);              // NN
    int*   rs_raw = (int*)(dinv + NN);                     // NN+1
    int*   csr_src   = rs_raw + NN + 1;                    // NE
    int*   gstart    = csr_src + NE;                       // NG+1
    float* stats = (float*)(gstart + NG + 1);              // 6*128 + 8 ctr
    float* pools = stats + 6 * HID + 8;                    // 2*NG*HID used
    float* psum  = pools + 3 * (size_t)NG * HID;           // AGB*128
    float* psq   = psum + (size_t)AGB * 128;               // AGB*128
    // transients live in the freed xb slot (12.8MB):
    int* deg   = (int*)xslot;                              // NN ints
    unsigned char* epos = (unsigned char*)(deg + NN);      // NE bytes
    int* bsums = (int*)(epos + NE);                        // NBLK ints
    int* row_fin = bsums + 512;                            // NN+1 ints (lives through all gathers)

    const int TB = 256;
    const int NB  = (NN + TB - 1) / TB;

    // frag-layout weight slots (W1 / s1_Wp formatted in-kernel by mega1)
    unsigned short* wfS1i  = wfb + 0 * 16384;
    unsigned short* wfS1o  = wfb + 1 * 16384;
    unsigned short* wfW2   = wfb + 2 * 16384;
    unsigned short* wfS2i  = wfb + 3 * 16384;
    unsigned short* wfS2o  = wfb + 4 * 16384;
    unsigned short* wfW3   = wfb + 5 * 16384;
    unsigned short* wfS3i  = wfb + 6 * 16384;
    unsigned short* wfS3o  = wfb + 7 * 16384;

    WPack wp;
    wp.w[0] = s1_Wi; wp.K[0] = HID;
    wp.w[1] = s1_Wo; wp.K[1] = HID;
    wp.w[2] = W2;    wp.K[2] = HID;
    wp.w[3] = s2_Wi; wp.K[3] = HID;
    wp.w[4] = s2_Wo; wp.K[4] = HID;
    wp.w[5] = W3;    wp.K[5] = HID;
    wp.w[6] = s3_Wi; wp.K[6] = HID;
    wp.w[7] = s3_Wo; wp.K[7] = HID;
    wp.w[8] = W2;    wp.K[8] = 0;
    wp.w[9] = W2;    wp.K[9] = 0;

    float* gsum1 = stats;            float* gsq1 = stats + HID;
    float* gsum2 = stats + 2 * HID;  float* gsq2 = stats + 3 * HID;
    float* gsum3 = stats + 4 * HID;  float* gsq3 = stats + 5 * HID;
    int*   ctrs  = (int*)(stats + 6 * HID);                // 3 used, zeroed in scan1

    // ---- mega1: degpos atomics || layer-1 dual GEMM || wprep || gstart ----
    hipMemsetAsync(deg, 0, NN * sizeof(int), stream);
    mega1_kernel<<<MEGA_TOT, TB, 0, stream>>>(src, dst, deg, epos, batch, gstart,
                                              x, W1, s1_Wp, wp, wfb, xwb, hb);
    scan1_kernel<<<NBLK, SCAN_B, 0, stream>>>(deg, rs_raw, bsums, dinv, stats);
    fill_kernel<<<FILL_B + NB, TB, 0, stream>>>(src, dst, rs_raw, bsums, epos,
                                                csr_src, row_fin);

    // ---- layer 1 (gather carries spin-tail stats reduce) ----
    gather_kernel<<<AGB + SRB, TB, 0, stream>>>(row_fin, csr_src, xwb, dinv, b1, aggb,
                                                psum, psq, gsum1, gsq1, ctrs + 0);
    mgemm_kernel<<<GB2K, TB, 0, stream>>>(aggb, wfS1o, HID, hb, wfS1i, HID,
                                          s1_bo, s1_bi, aggb, gsum1, gsq1, g1, be1, hb, 1,
                                          nullptr, nullptr);

    // ---- layer 2 (mode-2 GEMM carries pool1 blocks) ----
    mgemm_kernel<<<GB2K + NG, TB, 0, stream>>>(hb, wfW2, HID, nullptr, nullptr, 0,
                                               nullptr, nullptr, nullptr,
                                               nullptr, nullptr, nullptr, nullptr, xwb, 2,
                                               gstart, pools);
    gather_kernel<<<AGB + SRB, TB, 0, stream>>>(row_fin, csr_src, xwb, dinv, b2, aggb,
                                                psum, psq, gsum2, gsq2, ctrs + 1);
    mgemm_kernel<<<GB2K, TB, 0, stream>>>(aggb, wfS2o, HID, hb, wfS2i, HID,
                                          s2_bo, s2_bi, aggb, gsum2, gsq2, g2, be2, hb, 1,
                                          nullptr, nullptr);

    // ---- layer 3 (mode-2 GEMM carries pool2 blocks) ----
    mgemm_kernel<<<GB2K + NG, TB, 0, stream>>>(hb, wfW3, HID, nullptr, nullptr, 0,
                                               nullptr, nullptr, nullptr,
                                               nullptr, nullptr, nullptr, nullptr, xwb, 2,
                                               gstart, pools + (size_t)NG * HID);
    gather_kernel<<<AGB + SRB, TB, 0, stream>>>(row_fin, csr_src, xwb, dinv, b3, aggb,
                                                psum, psq, gsum3, gsq3, ctrs + 2);
    mgemm_kernel<<<GB2K, TB, 0, stream>>>(aggb, wfS3o, HID, hb, wfS3i, HID,
                                          s3_bo, s3_bi, aggb, gsum3, gsq3, g3, be3, hb, 1,
                                          nullptr, nullptr);

    // ---- head (vectorized pool3 fused) ----
    head_kernel<<<NG, TB, 0, stream>>>(pools, pools + (size_t)NG * HID,
                                       hb, gstart, eF,
                                       fc1W, fc1b, fc3W, fc3b, (float*)d_out);
}

// Round 8
// 701.460 us; speedup vs baseline: 7.4760x; 7.4760x over previous
//
#include <hip/hip_runtime.h>
#include <math.h>

#define NN 100000
#define NE 1600000
#define NG 1000
#define IN_DIM 64
#define HID 128
#define EXD 32
#define OUTD 10
#define BN_EPS 1e-5f

#define SCAN_B 256
#define NBLK ((NN + SCAN_B - 1) / SCAN_B)   // 391

// XCD-partitioned edge placement (scattered csr writes stay XCD-local)
#define FCH 128
#define FCE (NE / FCH)          // 12500 edges per chunk
#define PR  ((NN + 7) / 8)      // 12500 nodes per part

#define AGB 12500               // gather blocks (8 nodes each, exact)
#define SRB 1024                // stats-reduce blocks
#define SRC_CH ((AGB + SRB - 1) / SRB)   // 13 partial rows per block

#define GB2K ((NN + 127) / 128)          // 782 GEMM row-blocks

// mega1 grid layout: degpos(1024 edges/block) | mgemm2 | wprep | gstart
// roles INTERLEAVED via stride permutation; deg blocks carry 4 edges/thread.
#define MEGA_DEG ((NE + 1023) / 1024)    // 1563
#define MEGA_MG2 GB2K                    // 782
#define MEGA_WP  512                     // 8 matrices x 64
#define MEGA_GST NBLK                    // 391
#define MEGA_TOT (MEGA_DEG + MEGA_MG2 + MEGA_WP + MEGA_GST)   // 3248
#define MEGA_STRIDE 1023u                // gcd(1023, 3248) = 1 -> bijective

#define FILL_B (FCH * 8)                 // 1024

typedef __attribute__((ext_vector_type(8))) short bf16x8;
typedef __attribute__((ext_vector_type(4))) float f32x4;

__device__ __forceinline__ float bf2f(unsigned short h) {
    return __uint_as_float((unsigned int)h << 16);
}
__device__ __forceinline__ unsigned short f2bf(float f) {
    unsigned int u = __float_as_uint(f);
    u += 0x7fffu + ((u >> 16) & 1u);        // round to nearest even
    return (unsigned short)(u >> 16);
}

struct WPack {
    const float* w[10];
    int K[10];
};

#define CS_STRIDE 136
#define LW_STRIDE 1032          // shorts per k-chunk (1024 data + 8 pad)

// ---------------- mega1: degpos atomics || layer-1 dual GEMM || wprep || gstart ----------------
__launch_bounds__(256, 2)
__global__ void mega1_kernel(const int* __restrict__ src, const int* __restrict__ dst,
                             int* __restrict__ deg, unsigned char* __restrict__ epos,
                             const int* __restrict__ batch, int* __restrict__ gstart,
                             const float* __restrict__ x,
                             const float* __restrict__ W1raw, const float* __restrict__ Wpraw,
                             WPack wp, unsigned short* __restrict__ wf,
                             unsigned short* __restrict__ t0, unsigned short* __restrict__ t1) {
    __shared__ unsigned short sm[128 * CS_STRIDE];
    unsigned b = (unsigned)(((unsigned long long)blockIdx.x * MEGA_STRIDE) % MEGA_TOT);
    int tid = threadIdx.x;

    if (b < MEGA_DEG) {
        // 1024 edges/block, 4 independent atomics in flight per thread
        int e0 = b * 1024 + tid;
#pragma unroll
        for (int j = 0; j < 4; ++j) {
            int e = e0 + (j << 8);
            if (e < NE) epos[e] = (unsigned char)atomicAdd(&deg[dst[e]], 1);
        }
        return;
    }
    if (b < MEGA_DEG + MEGA_MG2) {
        // dual GEMM: t0 = bf16(x @ W1), t1 = bf16(x @ s1_Wp); A read as f32,
        // converted in-register. W formatted in-block from raw f32.
        int bb = (int)(b - MEGA_DEG);
        int lane = tid & 63;
        int wv = tid >> 6;
        int lane15 = lane & 15;
        int q = lane >> 4;
        int m0 = bb * 128 + wv * 32;

        for (int g = tid; g < 2048; g += 256) {
            int w = g >> 10, rem = g & 1023;
            int c = rem >> 7, n = rem & 127;
            const float* W = w ? Wpraw : W1raw;
            bf16x8 v;
#pragma unroll
            for (int j = 0; j < 8; ++j) v[j] = (short)f2bf(W[(c * 8 + j) * 128 + n]);
            *(bf16x8*)&sm[(w * 8 + c) * LW_STRIDE + n * 8] = v;
        }
        __syncthreads();

        f32x4 acc[2][2][8];
#pragma unroll
        for (int w = 0; w < 2; ++w)
#pragma unroll
            for (int r = 0; r < 2; ++r)
#pragma unroll
                for (int nt = 0; nt < 8; ++nt)
                    acc[w][r][nt] = (f32x4){0.f, 0.f, 0.f, 0.f};

        bf16x8 zf = {0, 0, 0, 0, 0, 0, 0, 0};
        int row0 = m0 + lane15;
        const float* a0p = x + (size_t)row0 * IN_DIM + (q << 3);
        const float* a1p = a0p + (size_t)16 * IN_DIM;
        bool g0 = row0 < NN, g1 = (row0 + 16) < NN;
#pragma unroll
        for (int k0 = 0; k0 < IN_DIM; k0 += 32) {
            bf16x8 af0 = zf, af1 = zf;
            if (g0) {
                float4 u0 = *(const float4*)(a0p + k0);
                float4 u1 = *(const float4*)(a0p + k0 + 4);
                af0[0] = (short)f2bf(u0.x); af0[1] = (short)f2bf(u0.y);
                af0[2] = (short)f2bf(u0.z); af0[3] = (short)f2bf(u0.w);
                af0[4] = (short)f2bf(u1.x); af0[5] = (short)f2bf(u1.y);
                af0[6] = (short)f2bf(u1.z); af0[7] = (short)f2bf(u1.w);
            }
            if (g1) {
                float4 u0 = *(const float4*)(a1p + k0);
                float4 u1 = *(const float4*)(a1p + k0 + 4);
                af1[0] = (short)f2bf(u0.x); af1[1] = (short)f2bf(u0.y);
                af1[2] = (short)f2bf(u0.z); af1[3] = (short)f2bf(u0.w);
                af1[4] = (short)f2bf(u1.x); af1[5] = (short)f2bf(u1.y);
                af1[6] = (short)f2bf(u1.z); af1[7] = (short)f2bf(u1.w);
            }
#pragma unroll
            for (int w = 0; w < 2; ++w) {
                const unsigned short* wb = &sm[(w * 8 + (k0 >> 3) + q) * LW_STRIDE + (lane15 << 3)];
#pragma unroll
                for (int nt = 0; nt < 8; ++nt) {
                    bf16x8 bf = *(const bf16x8*)(wb + nt * 128);
                    acc[w][0][nt] = __builtin_amdgcn_mfma_f32_16x16x32_bf16(af0, bf, acc[w][0][nt], 0, 0, 0);
                    acc[w][1][nt] = __builtin_amdgcn_mfma_f32_16x16x32_bf16(af1, bf, acc[w][1][nt], 0, 0, 0);
                }
            }
        }

        for (int w = 0; w < 2; ++w) {
            unsigned short* target = w ? t1 : t0;
            __syncthreads();
#pragma unroll
            for (int r = 0; r < 2; ++r)
#pragma unroll
                for (int nt = 0; nt < 8; ++nt)
#pragma unroll
                    for (int g = 0; g < 4; ++g) {
                        int rr = wv * 32 + r * 16 + q * 4 + g;
                        sm[rr * CS_STRIDE + nt * 16 + lane15] = f2bf(acc[w][r][nt][g]);
                    }
            __syncthreads();
#pragma unroll
            for (int i = 0; i < 8; ++i) {
                int rt = (tid >> 4) + i * 16;
                int ch = tid & 15;
                int row = bb * 128 + rt;
                if (row >= NN) continue;
                bf16x8 c = *(const bf16x8*)(sm + rt * CS_STRIDE + (ch << 3));
                *(bf16x8*)(target + (size_t)row * HID + (ch << 3)) = c;
            }
        }
        return;
    }
    if (b < MEGA_DEG + MEGA_MG2 + MEGA_WP) {
        int b2 = (int)(b - MEGA_DEG - MEGA_MG2);
        int m = b2 >> 6;
        int idx = ((b2 & 63) << 8) + tid;
        int K = wp.K[m];
        if (idx >= K * 128) return;
        int k = idx >> 7, n = idx & 127;
        wf[m * 16384 + (((k >> 3) * 128 + n) << 3) + (k & 7)] = f2bf(wp.w[m][idx]);
        return;
    }
    {
        int n = (int)(b - MEGA_DEG - MEGA_MG2 - MEGA_WP) * 256 + tid;
        if (n >= NN) return;
        int bc = batch[n];
        int bp = (n == 0) ? -1 : batch[n - 1];
        for (int g = bp + 1; g <= bc; ++g) gstart[g] = n;
        if (n == NN - 1)
            for (int g = bc + 1; g <= NG; ++g) gstart[g] = NN;
    }
}

// exclusive scan of deg -> rs_raw (per-block local); also dinv = rsqrt(deg+1)
// block 0 additionally zeroes the 6*128 BN-stat accumulators (memset folded in)
__global__ void scan1_kernel(const int* __restrict__ deg, int* __restrict__ rs_raw,
                             int* __restrict__ bsums, float* __restrict__ dinv,
                             float* __restrict__ stats_out) {
    __shared__ int s[SCAN_B];
    int t = threadIdx.x;
    int i = blockIdx.x * SCAN_B + t;
    if (blockIdx.x == 0) {
        stats_out[t] = 0.f; stats_out[t + 256] = 0.f; stats_out[t + 512] = 0.f;
    }
    int v = (i < NN) ? deg[i] : 0;
    if (i < NN) dinv[i] = rsqrtf((float)v + 1.0f);   // +1 self loop
    s[t] = v;
    __syncthreads();
    for (int off = 1; off < SCAN_B; off <<= 1) {
        int u = (t >= off) ? s[t - off] : 0;
        __syncthreads();
        s[t] += u;
        __syncthreads();
    }
    if (i < NN) rs_raw[i] = s[t] - v;
    if (t == SCAN_B - 1) bsums[blockIdx.x] = s[t];
}

// ---------------- fused: local bsums-scan + edge placement + row_start finalize ----------------
__global__ void fill_kernel(const int* __restrict__ src, const int* __restrict__ dst,
                            const int* __restrict__ rs_raw, const int* __restrict__ bsums,
                            const unsigned char* __restrict__ epos,
                            int* __restrict__ csr_src, int* __restrict__ row_fin) {
    __shared__ int sp[256];
    __shared__ int pfx[NBLK];
    int b = blockIdx.x;
    int tid = threadIdx.x;

    int b0v = (2 * tid < NBLK) ? bsums[2 * tid] : 0;
    int b1v = (2 * tid + 1 < NBLK) ? bsums[2 * tid + 1] : 0;
    sp[tid] = b0v + b1v;
    __syncthreads();
    for (int off = 1; off < 256; off <<= 1) {
        int u = (tid >= off) ? sp[tid - off] : 0;
        __syncthreads();
        sp[tid] += u;
        __syncthreads();
    }
    int excl = sp[tid] - b0v - b1v;      // sum of bsums[0 .. 2*tid-1]
    if (2 * tid < NBLK)     pfx[2 * tid]     = excl;
    if (2 * tid + 1 < NBLK) pfx[2 * tid + 1] = excl + b0v;
    __syncthreads();

    if (b < FILL_B) {
        int part = b & 7;
        int lo = part * PR, hi = min(lo + PR, NN);
        int e0 = (b >> 3) * FCE;
        for (int e = e0 + tid; e < e0 + FCE; e += 256) {
            int d = dst[e];
            if (d >= lo && d < hi)
                csr_src[rs_raw[d] + pfx[d >> 8] + (int)epos[e]] = src[e];
        }
    } else {
        int i = (b - FILL_B) * 256 + tid;
        if (i < NN) row_fin[i] = rs_raw[i] + pfx[i >> 8];
        if (i == 0) row_fin[NN] = NE;
    }
}

// ---------------- GCN aggregation: pull-gather + fused BN partial stats ----------------
// R5 form (verified 700.8us). R6 coop-shfl reverted (HW already broadcasts
// wave-uniform loads; gather is cache-BW-bound). R7 spin-tail reverted
// (tail blocks starved producers: 85% occ / 1.9% VALU / 20x slowdown).
__launch_bounds__(256)
__global__ void gather_kernel(const int* __restrict__ row_start,
                              const int* __restrict__ csr_src,
                              const unsigned short* __restrict__ xwb,
                              const float* __restrict__ dinv,
                              const float* __restrict__ b,
                              unsigned short* __restrict__ aggb,
                              float* __restrict__ psum, float* __restrict__ psq) {
    __shared__ float rsm[8][128];
    __shared__ float rqm[8][128];
    int node = blockIdx.x * 8 + (threadIdx.x >> 5);
    int lane = threadIdx.x & 31;
    int rs = row_start[node], re = row_start[node + 1];
    float d = dinv[node];
    int fo = lane << 2;
    ushort4 sv = *(const ushort4*)(xwb + (size_t)node * HID + fo);
    float4 accE = make_float4(0.f, 0.f, 0.f, 0.f);
    int e = rs;
    for (; e + 7 < re; e += 8) {
        int sI[8];
#pragma unroll
        for (int j = 0; j < 8; ++j) sI[j] = csr_src[e + j];
        float cI[8];
        ushort4 rI[8];
#pragma unroll
        for (int j = 0; j < 8; ++j) {
            cI[j] = dinv[sI[j]];
            rI[j] = *(const ushort4*)(xwb + (size_t)sI[j] * HID + fo);
        }
#pragma unroll
        for (int j = 0; j < 8; ++j) {
            accE.x += cI[j] * bf2f(rI[j].x);
            accE.y += cI[j] * bf2f(rI[j].y);
            accE.z += cI[j] * bf2f(rI[j].z);
            accE.w += cI[j] * bf2f(rI[j].w);
        }
    }
    for (; e + 1 < re; e += 2) {
        int s0 = csr_src[e], s1 = csr_src[e + 1];
        float c0 = dinv[s0], c1 = dinv[s1];
        ushort4 r0 = *(const ushort4*)(xwb + (size_t)s0 * HID + fo);
        ushort4 r1 = *(const ushort4*)(xwb + (size_t)s1 * HID + fo);
        accE.x += c0 * bf2f(r0.x) + c1 * bf2f(r1.x);
        accE.y += c0 * bf2f(r0.y) + c1 * bf2f(r1.y);
        accE.z += c0 * bf2f(r0.z) + c1 * bf2f(r1.z);
        accE.w += c0 * bf2f(r0.w) + c1 * bf2f(r1.w);
    }
    if (e < re) {
        int s0 = csr_src[e];
        float c0 = dinv[s0];
        ushort4 r0 = *(const ushort4*)(xwb + (size_t)s0 * HID + fo);
        accE.x += c0 * bf2f(r0.x);
        accE.y += c0 * bf2f(r0.y);
        accE.z += c0 * bf2f(r0.z);
        accE.w += c0 * bf2f(r0.w);
    }
    float d2 = d * d;
    ushort4 o;
    o.x = f2bf(d * accE.x + d2 * bf2f(sv.x) + b[fo + 0]);
    o.y = f2bf(d * accE.y + d2 * bf2f(sv.y) + b[fo + 1]);
    o.z = f2bf(d * accE.z + d2 * bf2f(sv.z) + b[fo + 2]);
    o.w = f2bf(d * accE.w + d2 * bf2f(sv.w) + b[fo + 3]);
    *(ushort4*)(aggb + (size_t)node * HID + fo) = o;

    // ---- fused BN partial stats (on the bf16-rounded values) ----
    float v0 = bf2f(o.x), v1 = bf2f(o.y), v2 = bf2f(o.z), v3 = bf2f(o.w);
    int sub = threadIdx.x >> 5;
    rsm[sub][fo + 0] = v0; rsm[sub][fo + 1] = v1;
    rsm[sub][fo + 2] = v2; rsm[sub][fo + 3] = v3;
    rqm[sub][fo + 0] = v0 * v0; rqm[sub][fo + 1] = v1 * v1;
    rqm[sub][fo + 2] = v2 * v2; rqm[sub][fo + 3] = v3 * v3;
    __syncthreads();
    int t = threadIdx.x;
    if (t < 128) {
        float s = 0.f, q = 0.f;
#pragma unroll
        for (int i = 0; i < 8; ++i) { s += rsm[i][t]; q += rqm[i][t]; }
        psum[(size_t)blockIdx.x * 128 + t] = s;
        psq[(size_t)blockIdx.x * 128 + t] = q;
    }
}

// reduce per-block partials -> gsum/gsq.
__global__ void stats_reduce_kernel(const float* __restrict__ psum,
                                    const float* __restrict__ psq,
                                    float* __restrict__ gsum, float* __restrict__ gsq) {
    int t = threadIdx.x;            // 256
    int c = t & 127;
    bool isq = t >= 128;
    const float* p = isq ? psq : psum;
    int b0 = blockIdx.x * SRC_CH;
    int b1 = min(b0 + SRC_CH, AGB);
    float s = 0.f;
    for (int bi = b0; bi < b1; ++bi)
        s += p[(size_t)bi * 128 + c];
    atomicAdd(isq ? &gsq[c] : &gsum[c], s);
}

// ---------------- MFMA GEMM (bf16 in, f32 acc, bf16 out) ----------------
// mode 2: target = bf16(A1 @ Wa); extra blocks [GB2K, GB2K+NG) do mean-pool of A1
// mode 1: BN finalize + gated-skip epilogue
__launch_bounds__(256, 4)
__global__ void mgemm_kernel(const unsigned short* __restrict__ A1,
                             const unsigned short* __restrict__ wfA, int K1,
                             const unsigned short* A2,
                             const unsigned short* __restrict__ wfB, int K2,
                             const float* __restrict__ bias1, const float* __restrict__ bias2,
                             const unsigned short* outx,
                             const float* __restrict__ gsum, const float* __restrict__ gsq,
                             const float* __restrict__ gw, const float* __restrict__ bew,
                             unsigned short* target, int mode,
                             const int* __restrict__ gst, float* __restrict__ poolout) {
    __shared__ unsigned short sm[128 * CS_STRIDE];   // W-stage / C-stage / pool-reduce
    int tid = threadIdx.x;

    if (mode == 2 && blockIdx.x >= GB2K) {
        // fused mean-pool over A1 (reads-only overlap with the GEMM blocks)
        float* red = (float*)sm;                      // 8 x 128 floats
        int g = blockIdx.x - GB2K;
        int lane = tid & 31, sub = tid >> 5;
        int s = gst[g], e = gst[g + 1];
        float4 acc = make_float4(0.f, 0.f, 0.f, 0.f);
        for (int r = s + sub; r < e; r += 8) {
            ushort4 v = *(const ushort4*)(A1 + (size_t)r * HID + (lane << 2));
            acc.x += bf2f(v.x); acc.y += bf2f(v.y);
            acc.z += bf2f(v.z); acc.w += bf2f(v.w);
        }
        *(float4*)&red[sub * 128 + (lane << 2)] = acc;
        __syncthreads();
        if (tid < 128) {
            float a = 0.f;
#pragma unroll
            for (int i = 0; i < 8; ++i) a += red[i * 128 + tid];
            poolout[(size_t)g * HID + tid] = a / (float)max(e - s, 1);
        }
        return;
    }

    __shared__ float sclS[128], shfS[128];
    int lane = tid & 63;
    int wv = tid >> 6;
    int lane15 = lane & 15;
    int q = lane >> 4;
    int m0 = blockIdx.x * 128 + wv * 32;

    if (mode == 1 && tid < 128) {
        float mu = gsum[tid] * (1.0f / NN);
        float var = gsq[tid] * (1.0f / NN) - mu * mu;
        float sc = gw[tid] * rsqrtf(var + BN_EPS);
        sclS[tid] = sc;
        shfS[tid] = bew[tid] - mu * sc;
    }

    f32x4 acc[2][8];
#pragma unroll
    for (int r = 0; r < 2; ++r)
#pragma unroll
        for (int nt = 0; nt < 8; ++nt)
            acc[r][nt] = (f32x4){0.f, 0.f, 0.f, 0.f};

    bf16x8 zf = {0, 0, 0, 0, 0, 0, 0, 0};

    for (int p = 0; p < 2; ++p) {
        const unsigned short* A = p ? A2 : A1;
        const unsigned short* wf = p ? wfB : wfA;
        int K = p ? K2 : K1;
        if (K == 0) continue;
        bool bnA = (mode == 1) && (p == 0);
        __syncthreads();
        for (int g = tid; g < K * 16; g += 256) {
            int c = g >> 7, off = (g & 127) << 3;
            *(bf16x8*)&sm[c * LW_STRIDE + off] = *(const bf16x8*)&wf[(c << 10) + off];
        }
        __syncthreads();
        int row0 = m0 + lane15;
        const unsigned short* a0p = A + (size_t)row0 * K + (q << 3);
        const unsigned short* a1p = a0p + (size_t)16 * K;
        bool g0 = row0 < NN, g1 = (row0 + 16) < NN;
#pragma unroll 4
        for (int k0 = 0; k0 < K; k0 += 32) {
            bf16x8 af0 = zf, af1 = zf;
            if (g0) af0 = *(const bf16x8*)(a0p + k0);
            if (g1) af1 = *(const bf16x8*)(a1p + k0);
            if (bnA) {
                int kb = k0 + (q << 3);
                float4 s4a = *(const float4*)&sclS[kb];
                float4 s4b = *(const float4*)&sclS[kb + 4];
                float4 h4a = *(const float4*)&shfS[kb];
                float4 h4b = *(const float4*)&shfS[kb + 4];
                float sv[8] = {s4a.x, s4a.y, s4a.z, s4a.w, s4b.x, s4b.y, s4b.z, s4b.w};
                float hv[8] = {h4a.x, h4a.y, h4a.z, h4a.w, h4b.x, h4b.y, h4b.z, h4b.w};
#pragma unroll
                for (int j = 0; j < 8; ++j) {
                    af0[j] = (short)f2bf(fmaxf(bf2f((unsigned short)af0[j]) * sv[j] + hv[j], 0.f));
                    af1[j] = (short)f2bf(fmaxf(bf2f((unsigned short)af1[j]) * sv[j] + hv[j], 0.f));
                }
            }
            const unsigned short* wb = &sm[((k0 >> 3) + q) * LW_STRIDE + (lane15 << 3)];
#pragma unroll
            for (int nt = 0; nt < 8; ++nt) {
                bf16x8 bf = *(const bf16x8*)(wb + nt * 128);
                acc[0][nt] = __builtin_amdgcn_mfma_f32_16x16x32_bf16(af0, bf, acc[0][nt], 0, 0, 0);
                acc[1][nt] = __builtin_amdgcn_mfma_f32_16x16x32_bf16(af1, bf, acc[1][nt], 0, 0, 0);
            }
        }
    }
    __syncthreads();

    if (mode == 1) {
        float bsum[8];
#pragma unroll
        for (int nt = 0; nt < 8; ++nt)
            bsum[nt] = bias1[nt * 16 + lane15] + bias2[nt * 16 + lane15];
#pragma unroll
        for (int r = 0; r < 2; ++r)
#pragma unroll
            for (int nt = 0; nt < 8; ++nt)
#pragma unroll
                for (int g = 0; g < 4; ++g) {
                    int rr = wv * 32 + r * 16 + q * 4 + g;
                    sm[rr * CS_STRIDE + nt * 16 + lane15] = f2bf(acc[r][nt][g] + bsum[nt]);
                }
    } else {
#pragma unroll
        for (int r = 0; r < 2; ++r)
#pragma unroll
            for (int nt = 0; nt < 8; ++nt)
#pragma unroll
                for (int g = 0; g < 4; ++g) {
                    int rr = wv * 32 + r * 16 + q * 4 + g;
                    sm[rr * CS_STRIDE + nt * 16 + lane15] = f2bf(acc[r][nt][g]);
                }
    }
    __syncthreads();

#pragma unroll
    for (int i = 0; i < 8; ++i) {
        int rt = (tid >> 4) + i * 16;
        int ch = tid & 15;
        int row = blockIdx.x * 128 + rt;
        if (row >= NN) continue;
        bf16x8 c = *(const bf16x8*)(sm + rt * CS_STRIDE + (ch << 3));
        size_t off = (size_t)row * HID + (ch << 3);
        if (mode == 1) {
            int cb = ch << 3;
            float4 s4a = *(const float4*)&sclS[cb];
            float4 s4b = *(const float4*)&sclS[cb + 4];
            float4 h4a = *(const float4*)&shfS[cb];
            float4 h4b = *(const float4*)&shfS[cb + 4];
            float sv[8] = {s4a.x, s4a.y, s4a.z, s4a.w, s4b.x, s4b.y, s4b.z, s4b.w};
            float hv[8] = {h4a.x, h4a.y, h4a.z, h4a.w, h4b.x, h4b.y, h4b.z, h4b.w};
            bf16x8 oxv = *(const bf16x8*)(outx + off);
            bf16x8 ixv = *(const bf16x8*)(target + off);
            bf16x8 o;
#pragma unroll
            for (int j = 0; j < 8; ++j) {
                float t = bf2f((unsigned short)c[j]);
                float z = 1.0f / (1.0f + expf(-t));
                float ox = fmaxf(bf2f((unsigned short)oxv[j]) * sv[j] + hv[j], 0.f);
                float h = z * ox + (1.0f - z) * bf2f((unsigned short)ixv[j]);
                o[j] = (short)f2bf(h);
            }
            *(bf16x8*)(target + off) = o;
        } else {
            *(bf16x8*)(target + off) = c;
        }
    }
}

// ---------------- MLP head with fused vectorized pool3 ----------------
__global__ void head_kernel(const float* __restrict__ pool1, const float* __restrict__ pool2,
                            const unsigned short* __restrict__ h3,
                            const int* __restrict__ gstart,
                            const float* __restrict__ eF,
                            const float* __restrict__ fc1W, const float* __restrict__ fc1b,
                            const float* __restrict__ fc3W, const float* __restrict__ fc3b,
                            float* __restrict__ out) {
    __shared__ float hg[3 * HID + EXD];
    __shared__ float hh[HID];
    __shared__ float red[8][128];
    int g = blockIdx.x, t = threadIdx.x;
    int lane = t & 31, sub = t >> 5;
    int s = gstart[g], e = gstart[g + 1];
    // vectorized mean-pool of h3 (8-sub x ushort4)
    float4 acc = make_float4(0.f, 0.f, 0.f, 0.f);
    for (int r = s + sub; r < e; r += 8) {
        ushort4 v = *(const ushort4*)(h3 + (size_t)r * HID + (lane << 2));
        acc.x += bf2f(v.x); acc.y += bf2f(v.y);
        acc.z += bf2f(v.z); acc.w += bf2f(v.w);
    }
    *(float4*)&red[sub][lane << 2] = acc;
    if (t < 128) {
        hg[t]       = pool1[(size_t)g * HID + t];
        hg[HID + t] = pool2[(size_t)g * HID + t];
    } else if (t < 128 + EXD) {
        hg[3 * HID + (t - 128)] = eF[(size_t)g * EXD + (t - 128)];
    }
    __syncthreads();
    if (t < 128) {
        float a = 0.f;
#pragma unroll
        for (int i = 0; i < 8; ++i) a += red[i][t];
        hg[2 * HID + t] = a / (float)max(e - s, 1);
    }
    __syncthreads();
    if (t < 128) {
        float a = fc1b[t];
        for (int k = 0; k < 3 * HID + EXD; ++k) a += hg[k] * fc1W[(size_t)k * HID + t];
        hh[t] = fmaxf(a, 0.f);
    }
    __syncthreads();
    if (t < OUTD) {
        float a2 = fc3b[t];
        for (int k = 0; k < HID; ++k) a2 += hh[k] * fc3W[(size_t)k * OUTD + t];
        out[(size_t)g * OUTD + t] = a2;
    }
}

// ---------------- launch ----------------

extern "C" void kernel_launch(void* const* d_in, const int* in_sizes, int n_in,
                              void* d_out, int out_size, void* d_ws, size_t ws_size,
                              hipStream_t stream) {
    const float* x      = (const float*)d_in[0];
    const float* eF     = (const float*)d_in[1];
    const int*   ei     = (const int*)d_in[2];
    const int*   batch  = (const int*)d_in[3];
    const int* src = ei;
    const int* dst = ei + NE;

    const float* W1 = (const float*)d_in[4];  const float* b1 = (const float*)d_in[5];
    const float* W2 = (const float*)d_in[6];  const float* b2 = (const float*)d_in[7];
    const float* W3 = (const float*)d_in[8];  const float* b3 = (const float*)d_in[9];
    const float* g1 = (const float*)d_in[10]; const float* be1 = (const float*)d_in[11];
    const float* g2 = (const float*)d_in[12]; const float* be2 = (const float*)d_in[13];
    const float* g3 = (const float*)d_in[14]; const float* be3 = (const float*)d_in[15];
    const float* s1_Wp = (const float*)d_in[16];
    const float* s1_Wi = (const float*)d_in[17]; const float* s1_bi = (const float*)d_in[18];
    const float* s1_Wo = (const float*)d_in[19]; const float* s1_bo = (const float*)d_in[20];
    const float* s2_Wi = (const float*)d_in[21]; const float* s2_bi = (const float*)d_in[22];
    const float* s2_Wo = (const float*)d_in[23]; const float* s2_bo = (const float*)d_in[24];
    const float* s3_Wi = (const float*)d_in[25]; const float* s3_bi = (const float*)d_in[26];
    const float* s3_Wo = (const float*)d_in[27]; const float* s3_bo = (const float*)d_in[28];
    const float* fc1W = (const float*)d_in[29]; const float* fc1b = (const float*)d_in[30];
    const float* fc3W = (const float*)d_in[31]; const float* fc3b = (const float*)d_in[32];

    size_t S = (size_t)NN * HID;
    unsigned short* xwb  = (unsigned short*)d_ws;          // NN*HID
    unsigned short* xslot = xwb + S;                       // freed xb slot -> transients
    unsigned short* hb   = xslot + (size_t)NN * IN_DIM;    // NN*HID
    unsigned short* aggb = hb + S;                         // NN*HID
    unsigned short* wfb  = aggb + S;                       // 8*16384 (10 slots reserved)
    float* dinv = (float*)(wfb + 10 * 16384);              // NN
    int*   rs_raw = (int*)(dinv + NN);                     // NN+1
    int*   csr_src   = rs_raw + NN + 1;                    // NE
    int*   gstart    = csr_src + NE;                       // NG+1
    float* stats = (float*)(gstart + NG + 1);              // 6*128
    float* pools = stats + 6 * HID;                        // 2*NG*HID used
    float* psum  = pools + 3 * (size_t)NG * HID;           // AGB*128
    float* psq   = psum + (size_t)AGB * 128;               // AGB*128
    // transients live in the freed xb slot (12.8MB):
    int* deg   = (int*)xslot;                              // NN ints
    unsigned char* epos = (unsigned char*)(deg + NN);      // NE bytes
    int* bsums = (int*)(epos + NE);                        // NBLK ints
    int* row_fin = bsums + 512;                            // NN+1 ints (lives through all gathers)

    const int TB = 256;
    const int NB  = (NN + TB - 1) / TB;

    // frag-layout weight slots (W1 / s1_Wp formatted in-kernel by mega1)
    unsigned short* wfS1i  = wfb + 0 * 16384;
    unsigned short* wfS1o  = wfb + 1 * 16384;
    unsigned short* wfW2   = wfb + 2 * 16384;
    unsigned short* wfS2i  = wfb + 3 * 16384;
    unsigned short* wfS2o  = wfb + 4 * 16384;
    unsigned short* wfW3   = wfb + 5 * 16384;
    unsigned short* wfS3i  = wfb + 6 * 16384;
    unsigned short* wfS3o  = wfb + 7 * 16384;

    WPack wp;
    wp.w[0] = s1_Wi; wp.K[0] = HID;
    wp.w[1] = s1_Wo; wp.K[1] = HID;
    wp.w[2] = W2;    wp.K[2] = HID;
    wp.w[3] = s2_Wi; wp.K[3] = HID;
    wp.w[4] = s2_Wo; wp.K[4] = HID;
    wp.w[5] = W3;    wp.K[5] = HID;
    wp.w[6] = s3_Wi; wp.K[6] = HID;
    wp.w[7] = s3_Wo; wp.K[7] = HID;
    wp.w[8] = W2;    wp.K[8] = 0;
    wp.w[9] = W2;    wp.K[9] = 0;

    float* gsum1 = stats;            float* gsq1 = stats + HID;
    float* gsum2 = stats + 2 * HID;  float* gsq2 = stats + 3 * HID;
    float* gsum3 = stats + 4 * HID;  float* gsq3 = stats + 5 * HID;

    // ---- mega1: degpos atomics || layer-1 dual GEMM || wprep || gstart ----
    hipMemsetAsync(deg, 0, NN * sizeof(int), stream);
    mega1_kernel<<<MEGA_TOT, TB, 0, stream>>>(src, dst, deg, epos, batch, gstart,
                                              x, W1, s1_Wp, wp, wfb, xwb, hb);
    scan1_kernel<<<NBLK, SCAN_B, 0, stream>>>(deg, rs_raw, bsums, dinv, stats);
    fill_kernel<<<FILL_B + NB, TB, 0, stream>>>(src, dst, rs_raw, bsums, epos,
                                                csr_src, row_fin);

    // ---- layer 1 ----
    gather_kernel<<<AGB, TB, 0, stream>>>(row_fin, csr_src, xwb, dinv, b1, aggb, psum, psq);
    stats_reduce_kernel<<<SRB, TB, 0, stream>>>(psum, psq, gsum1, gsq1);
    mgemm_kernel<<<GB2K, TB, 0, stream>>>(aggb, wfS1o, HID, hb, wfS1i, HID,
                                          s1_bo, s1_bi, aggb, gsum1, gsq1, g1, be1, hb, 1,
                                          nullptr, nullptr);

    // ---- layer 2 (mode-2 GEMM carries pool1 blocks) ----
    mgemm_kernel<<<GB2K + NG, TB, 0, stream>>>(hb, wfW2, HID, nullptr, nullptr, 0,
                                               nullptr, nullptr, nullptr,
                                               nullptr, nullptr, nullptr, nullptr, xwb, 2,
                                               gstart, pools);
    gather_kernel<<<AGB, TB, 0, stream>>>(row_fin, csr_src, xwb, dinv, b2, aggb, psum, psq);
    stats_reduce_kernel<<<SRB, TB, 0, stream>>>(psum, psq, gsum2, gsq2);
    mgemm_kernel<<<GB2K, TB, 0, stream>>>(aggb, wfS2o, HID, hb, wfS2i, HID,
                                          s2_bo, s2_bi, aggb, gsum2, gsq2, g2, be2, hb, 1,
                                          nullptr, nullptr);

    // ---- layer 3 (mode-2 GEMM carries pool2 blocks) ----
    mgemm_kernel<<<GB2K + NG, TB, 0, stream>>>(hb, wfW3, HID, nullptr, nullptr, 0,
                                               nullptr, nullptr, nullptr,
                                               nullptr, nullptr, nullptr, nullptr, xwb, 2,
                                               gstart, pools + (size_t)NG * HID);
    gather_kernel<<<AGB, TB, 0, stream>>>(row_fin, csr_src, xwb, dinv, b3, aggb, psum, psq);
    stats_reduce_kernel<<<SRB, TB, 0, stream>>>(psum, psq, gsum3, gsq3);
    mgemm_kernel<<<GB2K, TB, 0, stream>>>(aggb, wfS3o, HID, hb, wfS3i, HID,
                                          s3_bo, s3_bi, aggb, gsum3, gsq3, g3, be3, hb, 1,
                                          nullptr, nullptr);

    // ---- head (vectorized pool3 fused) ----
    head_kernel<<<NG, TB, 0, stream>>>(pools, pools + (size_t)NG * HID,
                                       hb, gstart, eF,
                                       fc1W, fc1b, fc3W, fc3b, (float*)d_out);
}

// Round 9
// 600.827 us; speedup vs baseline: 8.7282x; 1.1675x over previous
//
#include <hip/hip_runtime.h>
#include <math.h>

#define NN 100000
#define NE 1600000
#define NG 1000
#define IN_DIM 64
#define HID 128
#define EXD 32
#define OUTD 10
#define BN_EPS 1e-5f

#define SCAN_B 256
#define NBLK ((NN + SCAN_B - 1) / SCAN_B)   // 391

// XCD-partitioned edge placement (scattered csr writes stay XCD-local)
#define FCH 128
#define FCE (NE / FCH)          // 12500 edges per chunk
#define PR  ((NN + 7) / 8)      // 12500 nodes per part

#define AGB 12500               // gather blocks (8 nodes each, exact)
#define NSLOT 32                // BN-stat atomic slots (contention 12500/32 per addr)
#define PSTAT_L (2 * NSLOT * HID)   // floats per layer (sum + sq)

#define GB2K ((NN + 127) / 128)          // 782 GEMM row-blocks

// mega1 grid layout: degpos(1024 edges/block) | mgemm2 | wprep | gstart
// roles INTERLEAVED via stride permutation; deg blocks carry 4 edges/thread.
#define MEGA_DEG ((NE + 1023) / 1024)    // 1563
#define MEGA_MG2 GB2K                    // 782
#define MEGA_WP  512                     // 8 matrices x 64
#define MEGA_GST NBLK                    // 391
#define MEGA_TOT (MEGA_DEG + MEGA_MG2 + MEGA_WP + MEGA_GST)   // 3248
#define MEGA_STRIDE 1023u                // gcd(1023, 3248) = 1 -> bijective

#define FILL_B (FCH * 8)                 // 1024

typedef __attribute__((ext_vector_type(8))) short bf16x8;
typedef __attribute__((ext_vector_type(4))) float f32x4;

__device__ __forceinline__ float bf2f(unsigned short h) {
    return __uint_as_float((unsigned int)h << 16);
}
__device__ __forceinline__ unsigned short f2bf(float f) {
    unsigned int u = __float_as_uint(f);
    u += 0x7fffu + ((u >> 16) & 1u);        // round to nearest even
    return (unsigned short)(u >> 16);
}

struct WPack {
    const float* w[10];
    int K[10];
};

#define CS_STRIDE 136
#define LW_STRIDE 1032          // shorts per k-chunk (1024 data + 8 pad)

// ---------------- mega1: degpos atomics || layer-1 dual GEMM || wprep || gstart ----------------
__launch_bounds__(256, 2)
__global__ void mega1_kernel(const int* __restrict__ src, const int* __restrict__ dst,
                             int* __restrict__ deg, unsigned char* __restrict__ epos,
                             const int* __restrict__ batch, int* __restrict__ gstart,
                             const float* __restrict__ x,
                             const float* __restrict__ W1raw, const float* __restrict__ Wpraw,
                             WPack wp, unsigned short* __restrict__ wf,
                             unsigned short* __restrict__ t0, unsigned short* __restrict__ t1) {
    __shared__ unsigned short sm[128 * CS_STRIDE];
    unsigned b = (unsigned)(((unsigned long long)blockIdx.x * MEGA_STRIDE) % MEGA_TOT);
    int tid = threadIdx.x;

    if (b < MEGA_DEG) {
        // 1024 edges/block, 4 independent atomics in flight per thread
        int e0 = b * 1024 + tid;
#pragma unroll
        for (int j = 0; j < 4; ++j) {
            int e = e0 + (j << 8);
            if (e < NE) epos[e] = (unsigned char)atomicAdd(&deg[dst[e]], 1);
        }
        return;
    }
    if (b < MEGA_DEG + MEGA_MG2) {
        // dual GEMM: t0 = bf16(x @ W1), t1 = bf16(x @ s1_Wp); A read as f32,
        // converted in-register. W formatted in-block from raw f32.
        int bb = (int)(b - MEGA_DEG);
        int lane = tid & 63;
        int wv = tid >> 6;
        int lane15 = lane & 15;
        int q = lane >> 4;
        int m0 = bb * 128 + wv * 32;

        for (int g = tid; g < 2048; g += 256) {
            int w = g >> 10, rem = g & 1023;
            int c = rem >> 7, n = rem & 127;
            const float* W = w ? Wpraw : W1raw;
            bf16x8 v;
#pragma unroll
            for (int j = 0; j < 8; ++j) v[j] = (short)f2bf(W[(c * 8 + j) * 128 + n]);
            *(bf16x8*)&sm[(w * 8 + c) * LW_STRIDE + n * 8] = v;
        }
        __syncthreads();

        f32x4 acc[2][2][8];
#pragma unroll
        for (int w = 0; w < 2; ++w)
#pragma unroll
            for (int r = 0; r < 2; ++r)
#pragma unroll
                for (int nt = 0; nt < 8; ++nt)
                    acc[w][r][nt] = (f32x4){0.f, 0.f, 0.f, 0.f};

        bf16x8 zf = {0, 0, 0, 0, 0, 0, 0, 0};
        int row0 = m0 + lane15;
        const float* a0p = x + (size_t)row0 * IN_DIM + (q << 3);
        const float* a1p = a0p + (size_t)16 * IN_DIM;
        bool g0 = row0 < NN, g1 = (row0 + 16) < NN;
#pragma unroll
        for (int k0 = 0; k0 < IN_DIM; k0 += 32) {
            bf16x8 af0 = zf, af1 = zf;
            if (g0) {
                float4 u0 = *(const float4*)(a0p + k0);
                float4 u1 = *(const float4*)(a0p + k0 + 4);
                af0[0] = (short)f2bf(u0.x); af0[1] = (short)f2bf(u0.y);
                af0[2] = (short)f2bf(u0.z); af0[3] = (short)f2bf(u0.w);
                af0[4] = (short)f2bf(u1.x); af0[5] = (short)f2bf(u1.y);
                af0[6] = (short)f2bf(u1.z); af0[7] = (short)f2bf(u1.w);
            }
            if (g1) {
                float4 u0 = *(const float4*)(a1p + k0);
                float4 u1 = *(const float4*)(a1p + k0 + 4);
                af1[0] = (short)f2bf(u0.x); af1[1] = (short)f2bf(u0.y);
                af1[2] = (short)f2bf(u0.z); af1[3] = (short)f2bf(u0.w);
                af1[4] = (short)f2bf(u1.x); af1[5] = (short)f2bf(u1.y);
                af1[6] = (short)f2bf(u1.z); af1[7] = (short)f2bf(u1.w);
            }
#pragma unroll
            for (int w = 0; w < 2; ++w) {
                const unsigned short* wb = &sm[(w * 8 + (k0 >> 3) + q) * LW_STRIDE + (lane15 << 3)];
#pragma unroll
                for (int nt = 0; nt < 8; ++nt) {
                    bf16x8 bf = *(const bf16x8*)(wb + nt * 128);
                    acc[w][0][nt] = __builtin_amdgcn_mfma_f32_16x16x32_bf16(af0, bf, acc[w][0][nt], 0, 0, 0);
                    acc[w][1][nt] = __builtin_amdgcn_mfma_f32_16x16x32_bf16(af1, bf, acc[w][1][nt], 0, 0, 0);
                }
            }
        }

        for (int w = 0; w < 2; ++w) {
            unsigned short* target = w ? t1 : t0;
            __syncthreads();
#pragma unroll
            for (int r = 0; r < 2; ++r)
#pragma unroll
                for (int nt = 0; nt < 8; ++nt)
#pragma unroll
                    for (int g = 0; g < 4; ++g) {
                        int rr = wv * 32 + r * 16 + q * 4 + g;
                        sm[rr * CS_STRIDE + nt * 16 + lane15] = f2bf(acc[w][r][nt][g]);
                    }
            __syncthreads();
#pragma unroll
            for (int i = 0; i < 8; ++i) {
                int rt = (tid >> 4) + i * 16;
                int ch = tid & 15;
                int row = bb * 128 + rt;
                if (row >= NN) continue;
                bf16x8 c = *(const bf16x8*)(sm + rt * CS_STRIDE + (ch << 3));
                *(bf16x8*)(target + (size_t)row * HID + (ch << 3)) = c;
            }
        }
        return;
    }
    if (b < MEGA_DEG + MEGA_MG2 + MEGA_WP) {
        int b2 = (int)(b - MEGA_DEG - MEGA_MG2);
        int m = b2 >> 6;
        int idx = ((b2 & 63) << 8) + tid;
        int K = wp.K[m];
        if (idx >= K * 128) return;
        int k = idx >> 7, n = idx & 127;
        wf[m * 16384 + (((k >> 3) * 128 + n) << 3) + (k & 7)] = f2bf(wp.w[m][idx]);
        return;
    }
    {
        int n = (int)(b - MEGA_DEG - MEGA_MG2 - MEGA_WP) * 256 + tid;
        if (n >= NN) return;
        int bc = batch[n];
        int bp = (n == 0) ? -1 : batch[n - 1];
        for (int g = bp + 1; g <= bc; ++g) gstart[g] = n;
        if (n == NN - 1)
            for (int g = bc + 1; g <= NG; ++g) gstart[g] = NN;
    }
}

// exclusive scan of deg -> rs_raw (per-block local); also dinv = rsqrt(deg+1)
// blocks 0-95 zero the 3-layer slot-atomic BN-stat buffers (3*2*32*128 floats)
__global__ void scan1_kernel(const int* __restrict__ deg, int* __restrict__ rs_raw,
                             int* __restrict__ bsums, float* __restrict__ dinv,
                             float* __restrict__ pstat) {
    __shared__ int s[SCAN_B];
    int t = threadIdx.x;
    int i = blockIdx.x * SCAN_B + t;
    if (blockIdx.x < 96) pstat[blockIdx.x * 256 + t] = 0.f;   // 96*256 = 3*PSTAT_L
    int v = (i < NN) ? deg[i] : 0;
    if (i < NN) dinv[i] = rsqrtf((float)v + 1.0f);   // +1 self loop
    s[t] = v;
    __syncthreads();
    for (int off = 1; off < SCAN_B; off <<= 1) {
        int u = (t >= off) ? s[t - off] : 0;
        __syncthreads();
        s[t] += u;
        __syncthreads();
    }
    if (i < NN) rs_raw[i] = s[t] - v;
    if (t == SCAN_B - 1) bsums[blockIdx.x] = s[t];
}

// ---------------- fused: local bsums-scan + edge placement + row_start finalize ----------------
__global__ void fill_kernel(const int* __restrict__ src, const int* __restrict__ dst,
                            const int* __restrict__ rs_raw, const int* __restrict__ bsums,
                            const unsigned char* __restrict__ epos,
                            int* __restrict__ csr_src, int* __restrict__ row_fin) {
    __shared__ int sp[256];
    __shared__ int pfx[NBLK];
    int b = blockIdx.x;
    int tid = threadIdx.x;

    int b0v = (2 * tid < NBLK) ? bsums[2 * tid] : 0;
    int b1v = (2 * tid + 1 < NBLK) ? bsums[2 * tid + 1] : 0;
    sp[tid] = b0v + b1v;
    __syncthreads();
    for (int off = 1; off < 256; off <<= 1) {
        int u = (tid >= off) ? sp[tid - off] : 0;
        __syncthreads();
        sp[tid] += u;
        __syncthreads();
    }
    int excl = sp[tid] - b0v - b1v;      // sum of bsums[0 .. 2*tid-1]
    if (2 * tid < NBLK)     pfx[2 * tid]     = excl;
    if (2 * tid + 1 < NBLK) pfx[2 * tid + 1] = excl + b0v;
    __syncthreads();

    if (b < FILL_B) {
        int part = b & 7;
        int lo = part * PR, hi = min(lo + PR, NN);
        int e0 = (b >> 3) * FCE;
        for (int e = e0 + tid; e < e0 + FCE; e += 256) {
            int d = dst[e];
            if (d >= lo && d < hi)
                csr_src[rs_raw[d] + pfx[d >> 8] + (int)epos[e]] = src[e];
        }
    } else {
        int i = (b - FILL_B) * 256 + tid;
        if (i < NN) row_fin[i] = rs_raw[i] + pfx[i >> 8];
        if (i == 0) row_fin[NN] = NE;
    }
}

// ---------------- GCN aggregation: pull-gather + slot-atomic BN stats ----------------
// R9: per-block BN partial goes straight into 32 atomic slots (blockIdx&31)
// instead of a 12500-row partial buffer -> the 3 stats_reduce dispatches and
// their launch gaps are deleted. Contention: ~390 adds/address over ~65us.
__launch_bounds__(256)
__global__ void gather_kernel(const int* __restrict__ row_start,
                              const int* __restrict__ csr_src,
                              const unsigned short* __restrict__ xwb,
                              const float* __restrict__ dinv,
                              const float* __restrict__ b,
                              unsigned short* __restrict__ aggb,
                              float* __restrict__ pstatL) {
    __shared__ float rsm[8][128];
    __shared__ float rqm[8][128];
    int node = blockIdx.x * 8 + (threadIdx.x >> 5);
    int lane = threadIdx.x & 31;
    int rs = row_start[node], re = row_start[node + 1];
    float d = dinv[node];
    int fo = lane << 2;
    ushort4 sv = *(const ushort4*)(xwb + (size_t)node * HID + fo);
    float4 accE = make_float4(0.f, 0.f, 0.f, 0.f);
    int e = rs;
    for (; e + 7 < re; e += 8) {
        int sI[8];
#pragma unroll
        for (int j = 0; j < 8; ++j) sI[j] = csr_src[e + j];
        float cI[8];
        ushort4 rI[8];
#pragma unroll
        for (int j = 0; j < 8; ++j) {
            cI[j] = dinv[sI[j]];
            rI[j] = *(const ushort4*)(xwb + (size_t)sI[j] * HID + fo);
        }
#pragma unroll
        for (int j = 0; j < 8; ++j) {
            accE.x += cI[j] * bf2f(rI[j].x);
            accE.y += cI[j] * bf2f(rI[j].y);
            accE.z += cI[j] * bf2f(rI[j].z);
            accE.w += cI[j] * bf2f(rI[j].w);
        }
    }
    for (; e + 1 < re; e += 2) {
        int s0 = csr_src[e], s1 = csr_src[e + 1];
        float c0 = dinv[s0], c1 = dinv[s1];
        ushort4 r0 = *(const ushort4*)(xwb + (size_t)s0 * HID + fo);
        ushort4 r1 = *(const ushort4*)(xwb + (size_t)s1 * HID + fo);
        accE.x += c0 * bf2f(r0.x) + c1 * bf2f(r1.x);
        accE.y += c0 * bf2f(r0.y) + c1 * bf2f(r1.y);
        accE.z += c0 * bf2f(r0.z) + c1 * bf2f(r1.z);
        accE.w += c0 * bf2f(r0.w) + c1 * bf2f(r1.w);
    }
    if (e < re) {
        int s0 = csr_src[e];
        float c0 = dinv[s0];
        ushort4 r0 = *(const ushort4*)(xwb + (size_t)s0 * HID + fo);
        accE.x += c0 * bf2f(r0.x);
        accE.y += c0 * bf2f(r0.y);
        accE.z += c0 * bf2f(r0.z);
        accE.w += c0 * bf2f(r0.w);
    }
    float d2 = d * d;
    ushort4 o;
    o.x = f2bf(d * accE.x + d2 * bf2f(sv.x) + b[fo + 0]);
    o.y = f2bf(d * accE.y + d2 * bf2f(sv.y) + b[fo + 1]);
    o.z = f2bf(d * accE.z + d2 * bf2f(sv.z) + b[fo + 2]);
    o.w = f2bf(d * accE.w + d2 * bf2f(sv.w) + b[fo + 3]);
    *(ushort4*)(aggb + (size_t)node * HID + fo) = o;

    // ---- fused BN partial stats (on the bf16-rounded values) ----
    float v0 = bf2f(o.x), v1 = bf2f(o.y), v2 = bf2f(o.z), v3 = bf2f(o.w);
    int sub = threadIdx.x >> 5;
    rsm[sub][fo + 0] = v0; rsm[sub][fo + 1] = v1;
    rsm[sub][fo + 2] = v2; rsm[sub][fo + 3] = v3;
    rqm[sub][fo + 0] = v0 * v0; rqm[sub][fo + 1] = v1 * v1;
    rqm[sub][fo + 2] = v2 * v2; rqm[sub][fo + 3] = v3 * v3;
    __syncthreads();
    int t = threadIdx.x;
    if (t < 128) {
        float s = 0.f, q = 0.f;
#pragma unroll
        for (int i = 0; i < 8; ++i) { s += rsm[i][t]; q += rqm[i][t]; }
        int slot = blockIdx.x & (NSLOT - 1);
        atomicAdd(&pstatL[slot * 128 + t], s);
        atomicAdd(&pstatL[NSLOT * 128 + slot * 128 + t], q);
    }
}

// ---------------- MFMA GEMM (bf16 in, f32 acc, bf16 out) ----------------
// mode 2: target = bf16(A1 @ Wa); extra blocks [GB2K, GB2K+NG) do mean-pool of A1
// mode 1: BN finalize (reduce 32 atomic slots in-prologue) + gated-skip epilogue
__launch_bounds__(256, 4)
__global__ void mgemm_kernel(const unsigned short* __restrict__ A1,
                             const unsigned short* __restrict__ wfA, int K1,
                             const unsigned short* A2,
                             const unsigned short* __restrict__ wfB, int K2,
                             const float* __restrict__ bias1, const float* __restrict__ bias2,
                             const unsigned short* outx,
                             const float* __restrict__ pstatL,
                             const float* __restrict__ gw, const float* __restrict__ bew,
                             unsigned short* target, int mode,
                             const int* __restrict__ gst, float* __restrict__ poolout) {
    __shared__ unsigned short sm[128 * CS_STRIDE];   // W-stage / C-stage / pool-reduce
    int tid = threadIdx.x;

    if (mode == 2 && blockIdx.x >= GB2K) {
        // fused mean-pool over A1 (reads-only overlap with the GEMM blocks)
        float* red = (float*)sm;                      // 8 x 128 floats
        int g = blockIdx.x - GB2K;
        int lane = tid & 31, sub = tid >> 5;
        int s = gst[g], e = gst[g + 1];
        float4 acc = make_float4(0.f, 0.f, 0.f, 0.f);
        for (int r = s + sub; r < e; r += 8) {
            ushort4 v = *(const ushort4*)(A1 + (size_t)r * HID + (lane << 2));
            acc.x += bf2f(v.x); acc.y += bf2f(v.y);
            acc.z += bf2f(v.z); acc.w += bf2f(v.w);
        }
        *(float4*)&red[sub * 128 + (lane << 2)] = acc;
        __syncthreads();
        if (tid < 128) {
            float a = 0.f;
#pragma unroll
            for (int i = 0; i < 8; ++i) a += red[i * 128 + tid];
            poolout[(size_t)g * HID + tid] = a / (float)max(e - s, 1);
        }
        return;
    }

    __shared__ float sclS[128], shfS[128];
    int lane = tid & 63;
    int wv = tid >> 6;
    int lane15 = lane & 15;
    int q = lane >> 4;
    int m0 = blockIdx.x * 128 + wv * 32;

    if (mode == 1 && tid < 128) {
        float s = 0.f, qq = 0.f;
#pragma unroll
        for (int i = 0; i < NSLOT; ++i) {
            s  += pstatL[i * 128 + tid];
            qq += pstatL[NSLOT * 128 + i * 128 + tid];
        }
        float mu = s * (1.0f / NN);
        float var = qq * (1.0f / NN) - mu * mu;
        float sc = gw[tid] * rsqrtf(var + BN_EPS);
        sclS[tid] = sc;
        shfS[tid] = bew[tid] - mu * sc;
    }

    f32x4 acc[2][8];
#pragma unroll
    for (int r = 0; r < 2; ++r)
#pragma unroll
        for (int nt = 0; nt < 8; ++nt)
            acc[r][nt] = (f32x4){0.f, 0.f, 0.f, 0.f};

    bf16x8 zf = {0, 0, 0, 0, 0, 0, 0, 0};

    for (int p = 0; p < 2; ++p) {
        const unsigned short* A = p ? A2 : A1;
        const unsigned short* wf = p ? wfB : wfA;
        int K = p ? K2 : K1;
        if (K == 0) continue;
        bool bnA = (mode == 1) && (p == 0);
        __syncthreads();
        for (int g = tid; g < K * 16; g += 256) {
            int c = g >> 7, off = (g & 127) << 3;
            *(bf16x8*)&sm[c * LW_STRIDE + off] = *(const bf16x8*)&wf[(c << 10) + off];
        }
        __syncthreads();
        int row0 = m0 + lane15;
        const unsigned short* a0p = A + (size_t)row0 * K + (q << 3);
        const unsigned short* a1p = a0p + (size_t)16 * K;
        bool g0 = row0 < NN, g1 = (row0 + 16) < NN;
#pragma unroll 4
        for (int k0 = 0; k0 < K; k0 += 32) {
            bf16x8 af0 = zf, af1 = zf;
            if (g0) af0 = *(const bf16x8*)(a0p + k0);
            if (g1) af1 = *(const bf16x8*)(a1p + k0);
            if (bnA) {
                int kb = k0 + (q << 3);
                float4 s4a = *(const float4*)&sclS[kb];
                float4 s4b = *(const float4*)&sclS[kb + 4];
                float4 h4a = *(const float4*)&shfS[kb];
                float4 h4b = *(const float4*)&shfS[kb + 4];
                float sv[8] = {s4a.x, s4a.y, s4a.z, s4a.w, s4b.x, s4b.y, s4b.z, s4b.w};
                float hv[8] = {h4a.x, h4a.y, h4a.z, h4a.w, h4b.x, h4b.y, h4b.z, h4b.w};
#pragma unroll
                for (int j = 0; j < 8; ++j) {
                    af0[j] = (short)f2bf(fmaxf(bf2f((unsigned short)af0[j]) * sv[j] + hv[j], 0.f));
                    af1[j] = (short)f2bf(fmaxf(bf2f((unsigned short)af1[j]) * sv[j] + hv[j], 0.f));
                }
            }
            const unsigned short* wb = &sm[((k0 >> 3) + q) * LW_STRIDE + (lane15 << 3)];
#pragma unroll
            for (int nt = 0; nt < 8; ++nt) {
                bf16x8 bf = *(const bf16x8*)(wb + nt * 128);
                acc[0][nt] = __builtin_amdgcn_mfma_f32_16x16x32_bf16(af0, bf, acc[0][nt], 0, 0, 0);
                acc[1][nt] = __builtin_amdgcn_mfma_f32_16x16x32_bf16(af1, bf, acc[1][nt], 0, 0, 0);
            }
        }
    }
    __syncthreads();

    if (mode == 1) {
        float bsum[8];
#pragma unroll
        for (int nt = 0; nt < 8; ++nt)
            bsum[nt] = bias1[nt * 16 + lane15] + bias2[nt * 16 + lane15];
#pragma unroll
        for (int r = 0; r < 2; ++r)
#pragma unroll
            for (int nt = 0; nt < 8; ++nt)
#pragma unroll
                for (int g = 0; g < 4; ++g) {
                    int rr = wv * 32 + r * 16 + q * 4 + g;
                    sm[rr * CS_STRIDE + nt * 16 + lane15] = f2bf(acc[r][nt][g] + bsum[nt]);
                }
    } else {
#pragma unroll
        for (int r = 0; r < 2; ++r)
#pragma unroll
            for (int nt = 0; nt < 8; ++nt)
#pragma unroll
                for (int g = 0; g < 4; ++g) {
                    int rr = wv * 32 + r * 16 + q * 4 + g;
                    sm[rr * CS_STRIDE + nt * 16 + lane15] = f2bf(acc[r][nt][g]);
                }
    }
    __syncthreads();

#pragma unroll
    for (int i = 0; i < 8; ++i) {
        int rt = (tid >> 4) + i * 16;
        int ch = tid & 15;
        int row = blockIdx.x * 128 + rt;
        if (row >= NN) continue;
        bf16x8 c = *(const bf16x8*)(sm + rt * CS_STRIDE + (ch << 3));
        size_t off = (size_t)row * HID + (ch << 3);
        if (mode == 1) {
            int cb = ch << 3;
            float4 s4a = *(const float4*)&sclS[cb];
            float4 s4b = *(const float4*)&sclS[cb + 4];
            float4 h4a = *(const float4*)&shfS[cb];
            float4 h4b = *(const float4*)&shfS[cb + 4];
            float sv[8] = {s4a.x, s4a.y, s4a.z, s4a.w, s4b.x, s4b.y, s4b.z, s4b.w};
            float hv[8] = {h4a.x, h4a.y, h4a.z, h4a.w, h4b.x, h4b.y, h4b.z, h4b.w};
            bf16x8 oxv = *(const bf16x8*)(outx + off);
            bf16x8 ixv = *(const bf16x8*)(target + off);
            bf16x8 o;
#pragma unroll
            for (int j = 0; j < 8; ++j) {
                float t = bf2f((unsigned short)c[j]);
                float z = 1.0f / (1.0f + expf(-t));
                float ox = fmaxf(bf2f((unsigned short)oxv[j]) * sv[j] + hv[j], 0.f);
                float h = z * ox + (1.0f - z) * bf2f((unsigned short)ixv[j]);
                o[j] = (short)f2bf(h);
            }
            *(bf16x8*)(target + off) = o;
        } else {
            *(bf16x8*)(target + off) = c;
        }
    }
}

// ---------------- MLP head with fused vectorized pool3 ----------------
__global__ void head_kernel(const float* __restrict__ pool1, const float* __restrict__ pool2,
                            const unsigned short* __restrict__ h3,
                            const int* __restrict__ gstart,
                            const float* __restrict__ eF,
                            const float* __restrict__ fc1W, const float* __restrict__ fc1b,
                            const float* __restrict__ fc3W, const float* __restrict__ fc3b,
                            float* __restrict__ out) {
    __shared__ float hg[3 * HID + EXD];
    __shared__ float hh[HID];
    __shared__ float red[8][128];
    int g = blockIdx.x, t = threadIdx.x;
    int lane = t & 31, sub = t >> 5;
    int s = gstart[g], e = gstart[g + 1];
    // vectorized mean-pool of h3 (8-sub x ushort4)
    float4 acc = make_float4(0.f, 0.f, 0.f, 0.f);
    for (int r = s + sub; r < e; r += 8) {
        ushort4 v = *(const ushort4*)(h3 + (size_t)r * HID + (lane << 2));
        acc.x += bf2f(v.x); acc.y += bf2f(v.y);
        acc.z += bf2f(v.z); acc.w += bf2f(v.w);
    }
    *(float4*)&red[sub][lane << 2] = acc;
    if (t < 128) {
        hg[t]       = pool1[(size_t)g * HID + t];
        hg[HID + t] = pool2[(size_t)g * HID + t];
    } else if (t < 128 + EXD) {
        hg[3 * HID + (t - 128)] = eF[(size_t)g * EXD + (t - 128)];
    }
    __syncthreads();
    if (t < 128) {
        float a = 0.f;
#pragma unroll
        for (int i = 0; i < 8; ++i) a += red[i][t];
        hg[2 * HID + t] = a / (float)max(e - s, 1);
    }
    __syncthreads();
    if (t < 128) {
        float a = fc1b[t];
        for (int k = 0; k < 3 * HID + EXD; ++k) a += hg[k] * fc1W[(size_t)k * HID + t];
        hh[t] = fmaxf(a, 0.f);
    }
    __syncthreads();
    if (t < OUTD) {
        float a2 = fc3b[t];
        for (int k = 0; k < HID; ++k) a2 += hh[k] * fc3W[(size_t)k * OUTD + t];
        out[(size_t)g * OUTD + t] = a2;
    }
}

// ---------------- launch ----------------

extern "C" void kernel_launch(void* const* d_in, const int* in_sizes, int n_in,
                              void* d_out, int out_size, void* d_ws, size_t ws_size,
                              hipStream_t stream) {
    const float* x      = (const float*)d_in[0];
    const float* eF     = (const float*)d_in[1];
    const int*   ei     = (const int*)d_in[2];
    const int*   batch  = (const int*)d_in[3];
    const int* src = ei;
    const int* dst = ei + NE;

    const float* W1 = (const float*)d_in[4];  const float* b1 = (const float*)d_in[5];
    const float* W2 = (const float*)d_in[6];  const float* b2 = (const float*)d_in[7];
    const float* W3 = (const float*)d_in[8];  const float* b3 = (const float*)d_in[9];
    const float* g1 = (const float*)d_in[10]; const float* be1 = (const float*)d_in[11];
    const float* g2 = (const float*)d_in[12]; const float* be2 = (const float*)d_in[13];
    const float* g3 = (const float*)d_in[14]; const float* be3 = (const float*)d_in[15];
    const float* s1_Wp = (const float*)d_in[16];
    const float* s1_Wi = (const float*)d_in[17]; const float* s1_bi = (const float*)d_in[18];
    const float* s1_Wo = (const float*)d_in[19]; const float* s1_bo = (const float*)d_in[20];
    const float* s2_Wi = (const float*)d_in[21]; const float* s2_bi = (const float*)d_in[22];
    const float* s2_Wo = (const float*)d_in[23]; const float* s2_bo = (const float*)d_in[24];
    const float* s3_Wi = (const float*)d_in[25]; const float* s3_bi = (const float*)d_in[26];
    const float* s3_Wo = (const float*)d_in[27]; const float* s3_bo = (const float*)d_in[28];
    const float* fc1W = (const float*)d_in[29]; const float* fc1b = (const float*)d_in[30];
    const float* fc3W = (const float*)d_in[31]; const float* fc3b = (const float*)d_in[32];

    size_t S = (size_t)NN * HID;
    unsigned short* xwb  = (unsigned short*)d_ws;          // NN*HID
    unsigned short* xslot = xwb + S;                       // freed xb slot -> transients
    unsigned short* hb   = xslot + (size_t)NN * IN_DIM;    // NN*HID
    unsigned short* aggb = hb + S;                         // NN*HID
    unsigned short* wfb  = aggb + S;                       // 8*16384 (10 slots reserved)
    float* dinv = (float*)(wfb + 10 * 16384);              // NN
    int*   rs_raw = (int*)(dinv + NN);                     // NN+1
    int*   csr_src   = rs_raw + NN + 1;                    // NE
    int*   gstart    = csr_src + NE;                       // NG+1
    float* pstat = (float*)(gstart + NG + 1);              // 3 * PSTAT_L floats
    float* pools = pstat + 3 * PSTAT_L;                    // 2*NG*HID used
    // transients live in the freed xb slot (12.8MB):
    int* deg   = (int*)xslot;                              // NN ints
    unsigned char* epos = (unsigned char*)(deg + NN);      // NE bytes
    int* bsums = (int*)(epos + NE);                        // NBLK ints
    int* row_fin = bsums + 512;                            // NN+1 ints (lives through all gathers)

    const int TB = 256;
    const int NB  = (NN + TB - 1) / TB;

    // frag-layout weight slots (W1 / s1_Wp formatted in-kernel by mega1)
    unsigned short* wfS1i  = wfb + 0 * 16384;
    unsigned short* wfS1o  = wfb + 1 * 16384;
    unsigned short* wfW2   = wfb + 2 * 16384;
    unsigned short* wfS2i  = wfb + 3 * 16384;
    unsigned short* wfS2o  = wfb + 4 * 16384;
    unsigned short* wfW3   = wfb + 5 * 16384;
    unsigned short* wfS3i  = wfb + 6 * 16384;
    unsigned short* wfS3o  = wfb + 7 * 16384;

    WPack wp;
    wp.w[0] = s1_Wi; wp.K[0] = HID;
    wp.w[1] = s1_Wo; wp.K[1] = HID;
    wp.w[2] = W2;    wp.K[2] = HID;
    wp.w[3] = s2_Wi; wp.K[3] = HID;
    wp.w[4] = s2_Wo; wp.K[4] = HID;
    wp.w[5] = W3;    wp.K[5] = HID;
    wp.w[6] = s3_Wi; wp.K[6] = HID;
    wp.w[7] = s3_Wo; wp.K[7] = HID;
    wp.w[8] = W2;    wp.K[8] = 0;
    wp.w[9] = W2;    wp.K[9] = 0;

    float* pst1 = pstat;
    float* pst2 = pstat + PSTAT_L;
    float* pst3 = pstat + 2 * PSTAT_L;

    // ---- mega1: degpos atomics || layer-1 dual GEMM || wprep || gstart ----
    hipMemsetAsync(deg, 0, NN * sizeof(int), stream);
    mega1_kernel<<<MEGA_TOT, TB, 0, stream>>>(src, dst, deg, epos, batch, gstart,
                                              x, W1, s1_Wp, wp, wfb, xwb, hb);
    scan1_kernel<<<NBLK, SCAN_B, 0, stream>>>(deg, rs_raw, bsums, dinv, pstat);
    fill_kernel<<<FILL_B + NB, TB, 0, stream>>>(src, dst, rs_raw, bsums, epos,
                                                csr_src, row_fin);

    // ---- layer 1 ----
    gather_kernel<<<AGB, TB, 0, stream>>>(row_fin, csr_src, xwb, dinv, b1, aggb, pst1);
    mgemm_kernel<<<GB2K, TB, 0, stream>>>(aggb, wfS1o, HID, hb, wfS1i, HID,
                                          s1_bo, s1_bi, aggb, pst1, g1, be1, hb, 1,
                                          nullptr, nullptr);

    // ---- layer 2 (mode-2 GEMM carries pool1 blocks) ----
    mgemm_kernel<<<GB2K + NG, TB, 0, stream>>>(hb, wfW2, HID, nullptr, nullptr, 0,
                                               nullptr, nullptr, nullptr,
                                               nullptr, nullptr, nullptr, xwb, 2,
                                               gstart, pools);
    gather_kernel<<<AGB, TB, 0, stream>>>(row_fin, csr_src, xwb, dinv, b2, aggb, pst2);
    mgemm_kernel<<<GB2K, TB, 0, stream>>>(aggb, wfS2o, HID, hb, wfS2i, HID,
                                          s2_bo, s2_bi, aggb, pst2, g2, be2, hb, 1,
                                          nullptr, nullptr);

    // ---- layer 3 (mode-2 GEMM carries pool2 blocks) ----
    mgemm_kernel<<<GB2K + NG, TB, 0, stream>>>(hb, wfW3, HID, nullptr, nullptr, 0,
                                               nullptr, nullptr, nullptr,
                                               nullptr, nullptr, nullptr, xwb, 2,
                                               gstart, pools + (size_t)NG * HID);
    gather_kernel<<<AGB, TB, 0, stream>>>(row_fin, csr_src, xwb, dinv, b3, aggb, pst3);
    mgemm_kernel<<<GB2K, TB, 0, stream>>>(aggb, wfS3o, HID, hb, wfS3i, HID,
                                          s3_bo, s3_bi, aggb, pst3, g3, be3, hb, 1,
                                          nullptr, nullptr);

    // ---- head (vectorized pool3 fused) ----
    head_kernel<<<NG, TB, 0, stream>>>(pools, pools + (size_t)NG * HID,
                                       hb, gstart, eF,
                                       fc1W, fc1b, fc3W, fc3b, (float*)d_out);
}

// Round 10
// 597.639 us; speedup vs baseline: 8.7747x; 1.0053x over previous
//
#include <hip/hip_runtime.h>
#include <math.h>

#define NN 100000
#define NE 1600000
#define NG 1000
#define IN_DIM 64
#define HID 128
#define EXD 32
#define OUTD 10
#define BN_EPS 1e-5f

#define SCAN_B 256
#define NBLK ((NN + SCAN_B - 1) / SCAN_B)   // 391

// XCD-partitioned edge placement (scattered csr writes stay XCD-local)
#define FCH 128
#define FCE (NE / FCH)          // 12500 edges per chunk
#define PR  ((NN + 7) / 8)      // 12500 nodes per part

#define AGB 12500               // gather blocks (8 nodes each, exact)
#define NSLOT 32                // BN-stat atomic slots
#define PSTAT_L (2 * NSLOT * HID)   // floats per layer (sum + sq)

#define GB2K ((NN + 127) / 128)          // 782 GEMM row-blocks

// mega1 grid layout: degpos(1024 edges/block) | mgemm2 | wprep | gstart
#define MEGA_DEG ((NE + 1023) / 1024)    // 1563
#define MEGA_MG2 GB2K                    // 782
#define MEGA_WP  512                     // 8 matrices x 64
#define MEGA_GST NBLK                    // 391
#define MEGA_TOT (MEGA_DEG + MEGA_MG2 + MEGA_WP + MEGA_GST)   // 3248
#define MEGA_STRIDE 1023u                // gcd(1023, 3248) = 1 -> bijective

#define FILL_B (FCH * 8)                 // 1024

typedef __attribute__((ext_vector_type(8))) short bf16x8;
typedef __attribute__((ext_vector_type(4))) float f32x4;

__device__ __forceinline__ float bf2f(unsigned short h) {
    return __uint_as_float((unsigned int)h << 16);
}
__device__ __forceinline__ unsigned short f2bf(float f) {
    unsigned int u = __float_as_uint(f);
    u += 0x7fffu + ((u >> 16) & 1u);        // round to nearest even
    return (unsigned short)(u >> 16);
}

struct WPack {
    const float* w[10];
    int K[10];
};

#define CS_STRIDE 136
#define LW_STRIDE 1032          // shorts per k-chunk (1024 data + 8 pad)

// ---------------- mega1: degpos atomics || layer-1 dual GEMM || wprep || gstart ----------------
__launch_bounds__(256, 2)
__global__ void mega1_kernel(const int* __restrict__ src, const int* __restrict__ dst,
                             int* __restrict__ deg, unsigned char* __restrict__ epos,
                             const int* __restrict__ batch, int* __restrict__ gstart,
                             const float* __restrict__ x,
                             const float* __restrict__ W1raw, const float* __restrict__ Wpraw,
                             WPack wp, unsigned short* __restrict__ wf,
                             unsigned short* __restrict__ t0, unsigned short* __restrict__ t1) {
    __shared__ unsigned short sm[128 * CS_STRIDE];
    unsigned b = (unsigned)(((unsigned long long)blockIdx.x * MEGA_STRIDE) % MEGA_TOT);
    int tid = threadIdx.x;

    if (b < MEGA_DEG) {
        // 1024 edges/block, 4 independent atomics in flight per thread
        int e0 = b * 1024 + tid;
#pragma unroll
        for (int j = 0; j < 4; ++j) {
            int e = e0 + (j << 8);
            if (e < NE) epos[e] = (unsigned char)atomicAdd(&deg[dst[e]], 1);
        }
        return;
    }
    if (b < MEGA_DEG + MEGA_MG2) {
        // dual GEMM: t0 = bf16(x @ W1), t1 = bf16(x @ s1_Wp)
        int bb = (int)(b - MEGA_DEG);
        int lane = tid & 63;
        int wv = tid >> 6;
        int lane15 = lane & 15;
        int q = lane >> 4;
        int m0 = bb * 128 + wv * 32;

        for (int g = tid; g < 2048; g += 256) {
            int w = g >> 10, rem = g & 1023;
            int c = rem >> 7, n = rem & 127;
            const float* W = w ? Wpraw : W1raw;
            bf16x8 v;
#pragma unroll
            for (int j = 0; j < 8; ++j) v[j] = (short)f2bf(W[(c * 8 + j) * 128 + n]);
            *(bf16x8*)&sm[(w * 8 + c) * LW_STRIDE + n * 8] = v;
        }
        __syncthreads();

        f32x4 acc[2][2][8];
#pragma unroll
        for (int w = 0; w < 2; ++w)
#pragma unroll
            for (int r = 0; r < 2; ++r)
#pragma unroll
                for (int nt = 0; nt < 8; ++nt)
                    acc[w][r][nt] = (f32x4){0.f, 0.f, 0.f, 0.f};

        bf16x8 zf = {0, 0, 0, 0, 0, 0, 0, 0};
        int row0 = m0 + lane15;
        const float* a0p = x + (size_t)row0 * IN_DIM + (q << 3);
        const float* a1p = a0p + (size_t)16 * IN_DIM;
        bool g0 = row0 < NN, g1 = (row0 + 16) < NN;
#pragma unroll
        for (int k0 = 0; k0 < IN_DIM; k0 += 32) {
            bf16x8 af0 = zf, af1 = zf;
            if (g0) {
                float4 u0 = *(const float4*)(a0p + k0);
                float4 u1 = *(const float4*)(a0p + k0 + 4);
                af0[0] = (short)f2bf(u0.x); af0[1] = (short)f2bf(u0.y);
                af0[2] = (short)f2bf(u0.z); af0[3] = (short)f2bf(u0.w);
                af0[4] = (short)f2bf(u1.x); af0[5] = (short)f2bf(u1.y);
                af0[6] = (short)f2bf(u1.z); af0[7] = (short)f2bf(u1.w);
            }
            if (g1) {
                float4 u0 = *(const float4*)(a1p + k0);
                float4 u1 = *(const float4*)(a1p + k0 + 4);
                af1[0] = (short)f2bf(u0.x); af1[1] = (short)f2bf(u0.y);
                af1[2] = (short)f2bf(u0.z); af1[3] = (short)f2bf(u0.w);
                af1[4] = (short)f2bf(u1.x); af1[5] = (short)f2bf(u1.y);
                af1[6] = (short)f2bf(u1.z); af1[7] = (short)f2bf(u1.w);
            }
#pragma unroll
            for (int w = 0; w < 2; ++w) {
                const unsigned short* wb = &sm[(w * 8 + (k0 >> 3) + q) * LW_STRIDE + (lane15 << 3)];
#pragma unroll
                for (int nt = 0; nt < 8; ++nt) {
                    bf16x8 bf = *(const bf16x8*)(wb + nt * 128);
                    acc[w][0][nt] = __builtin_amdgcn_mfma_f32_16x16x32_bf16(af0, bf, acc[w][0][nt], 0, 0, 0);
                    acc[w][1][nt] = __builtin_amdgcn_mfma_f32_16x16x32_bf16(af1, bf, acc[w][1][nt], 0, 0, 0);
                }
            }
        }

        for (int w = 0; w < 2; ++w) {
            unsigned short* target = w ? t1 : t0;
            __syncthreads();
#pragma unroll
            for (int r = 0; r < 2; ++r)
#pragma unroll
                for (int nt = 0; nt < 8; ++nt)
#pragma unroll
                    for (int g = 0; g < 4; ++g) {
                        int rr = wv * 32 + r * 16 + q * 4 + g;
                        sm[rr * CS_STRIDE + nt * 16 + lane15] = f2bf(acc[w][r][nt][g]);
                    }
            __syncthreads();
#pragma unroll
            for (int i = 0; i < 8; ++i) {
                int rt = (tid >> 4) + i * 16;
                int ch = tid & 15;
                int row = bb * 128 + rt;
                if (row >= NN) continue;
                bf16x8 c = *(const bf16x8*)(sm + rt * CS_STRIDE + (ch << 3));
                *(bf16x8*)(target + (size_t)row * HID + (ch << 3)) = c;
            }
        }
        return;
    }
    if (b < MEGA_DEG + MEGA_MG2 + MEGA_WP) {
        int b2 = (int)(b - MEGA_DEG - MEGA_MG2);
        int m = b2 >> 6;
        int idx = ((b2 & 63) << 8) + tid;
        int K = wp.K[m];
        if (idx >= K * 128) return;
        int k = idx >> 7, n = idx & 127;
        wf[m * 16384 + (((k >> 3) * 128 + n) << 3) + (k & 7)] = f2bf(wp.w[m][idx]);
        return;
    }
    {
        int n = (int)(b - MEGA_DEG - MEGA_MG2 - MEGA_WP) * 256 + tid;
        if (n >= NN) return;
        int bc = batch[n];
        int bp = (n == 0) ? -1 : batch[n - 1];
        for (int g = bp + 1; g <= bc; ++g) gstart[g] = n;
        if (n == NN - 1)
            for (int g = bc + 1; g <= NG; ++g) gstart[g] = NN;
    }
}

// exclusive scan of deg -> rs_raw; also dinv = rsqrt(deg+1)
// blocks 0-95 zero the 3-layer slot-atomic BN-stat buffers
__global__ void scan1_kernel(const int* __restrict__ deg, int* __restrict__ rs_raw,
                             int* __restrict__ bsums, float* __restrict__ dinv,
                             float* __restrict__ pstat) {
    __shared__ int s[SCAN_B];
    int t = threadIdx.x;
    int i = blockIdx.x * SCAN_B + t;
    if (blockIdx.x < 96) pstat[blockIdx.x * 256 + t] = 0.f;   // 96*256 = 3*PSTAT_L
    int v = (i < NN) ? deg[i] : 0;
    if (i < NN) dinv[i] = rsqrtf((float)v + 1.0f);   // +1 self loop
    s[t] = v;
    __syncthreads();
    for (int off = 1; off < SCAN_B; off <<= 1) {
        int u = (t >= off) ? s[t - off] : 0;
        __syncthreads();
        s[t] += u;
        __syncthreads();
    }
    if (i < NN) rs_raw[i] = s[t] - v;
    if (t == SCAN_B - 1) bsums[blockIdx.x] = s[t];
}

// ---------------- fused: local bsums-scan + edge placement + row_start finalize ----------------
__global__ void fill_kernel(const int* __restrict__ src, const int* __restrict__ dst,
                            const int* __restrict__ rs_raw, const int* __restrict__ bsums,
                            const unsigned char* __restrict__ epos,
                            int* __restrict__ csr_src, int* __restrict__ row_fin) {
    __shared__ int sp[256];
    __shared__ int pfx[NBLK];
    int b = blockIdx.x;
    int tid = threadIdx.x;

    int b0v = (2 * tid < NBLK) ? bsums[2 * tid] : 0;
    int b1v = (2 * tid + 1 < NBLK) ? bsums[2 * tid + 1] : 0;
    sp[tid] = b0v + b1v;
    __syncthreads();
    for (int off = 1; off < 256; off <<= 1) {
        int u = (tid >= off) ? sp[tid - off] : 0;
        __syncthreads();
        sp[tid] += u;
        __syncthreads();
    }
    int excl = sp[tid] - b0v - b1v;
    if (2 * tid < NBLK)     pfx[2 * tid]     = excl;
    if (2 * tid + 1 < NBLK) pfx[2 * tid + 1] = excl + b0v;
    __syncthreads();

    if (b < FILL_B) {
        int part = b & 7;
        int lo = part * PR, hi = min(lo + PR, NN);
        int e0 = (b >> 3) * FCE;
        for (int e = e0 + tid; e < e0 + FCE; e += 256) {
            int d = dst[e];
            if (d >= lo && d < hi)
                csr_src[rs_raw[d] + pfx[d >> 8] + (int)epos[e]] = src[e];
        }
    } else {
        int i = (b - FILL_B) * 256 + tid;
        if (i < NN) row_fin[i] = rs_raw[i] + pfx[i >> 8];
        if (i == 0) row_fin[NN] = NE;
    }
}

// ---------------- GCN aggregation: pull-gather + slot-atomic BN stats ----------------
// tail blocks [AGB, AGB+NG) (when poolout != null): mean-pool of hsrc
// (complete before launch; R3-verified rider pattern).
__launch_bounds__(256)
__global__ void gather_kernel(const int* __restrict__ row_start,
                              const int* __restrict__ csr_src,
                              const unsigned short* __restrict__ xwb,
                              const float* __restrict__ dinv,
                              const float* __restrict__ b,
                              unsigned short* __restrict__ aggb,
                              float* __restrict__ pstatL,
                              const unsigned short* __restrict__ hsrc,
                              const int* __restrict__ gst,
                              float* __restrict__ poolout) {
    __shared__ float rsm[8][128];
    __shared__ float rqm[8][128];

    if (poolout != nullptr && blockIdx.x >= AGB) {
        int g = blockIdx.x - AGB;
        int t = threadIdx.x;
        int lane = t & 31, sub = t >> 5;
        int s = gst[g], e = gst[g + 1];
        float4 acc = make_float4(0.f, 0.f, 0.f, 0.f);
        for (int r = s + sub; r < e; r += 8) {
            ushort4 v = *(const ushort4*)(hsrc + (size_t)r * HID + (lane << 2));
            acc.x += bf2f(v.x); acc.y += bf2f(v.y);
            acc.z += bf2f(v.z); acc.w += bf2f(v.w);
        }
        *(float4*)&rsm[sub][lane << 2] = acc;
        __syncthreads();
        if (t < 128) {
            float a = 0.f;
#pragma unroll
            for (int i = 0; i < 8; ++i) a += rsm[i][t];
            poolout[(size_t)g * HID + t] = a / (float)max(e - s, 1);
        }
        return;
    }

    int node = blockIdx.x * 8 + (threadIdx.x >> 5);
    int lane = threadIdx.x & 31;
    int rs = row_start[node], re = row_start[node + 1];
    float d = dinv[node];
    int fo = lane << 2;
    ushort4 sv = *(const ushort4*)(xwb + (size_t)node * HID + fo);
    float4 accE = make_float4(0.f, 0.f, 0.f, 0.f);
    int e = rs;
    for (; e + 7 < re; e += 8) {
        int sI[8];
#pragma unroll
        for (int j = 0; j < 8; ++j) sI[j] = csr_src[e + j];
        float cI[8];
        ushort4 rI[8];
#pragma unroll
        for (int j = 0; j < 8; ++j) {
            cI[j] = dinv[sI[j]];
            rI[j] = *(const ushort4*)(xwb + (size_t)sI[j] * HID + fo);
        }
#pragma unroll
        for (int j = 0; j < 8; ++j) {
            accE.x += cI[j] * bf2f(rI[j].x);
            accE.y += cI[j] * bf2f(rI[j].y);
            accE.z += cI[j] * bf2f(rI[j].z);
            accE.w += cI[j] * bf2f(rI[j].w);
        }
    }
    for (; e + 1 < re; e += 2) {
        int s0 = csr_src[e], s1 = csr_src[e + 1];
        float c0 = dinv[s0], c1 = dinv[s1];
        ushort4 r0 = *(const ushort4*)(xwb + (size_t)s0 * HID + fo);
        ushort4 r1 = *(const ushort4*)(xwb + (size_t)s1 * HID + fo);
        accE.x += c0 * bf2f(r0.x) + c1 * bf2f(r1.x);
        accE.y += c0 * bf2f(r0.y) + c1 * bf2f(r1.y);
        accE.z += c0 * bf2f(r0.z) + c1 * bf2f(r1.z);
        accE.w += c0 * bf2f(r0.w) + c1 * bf2f(r1.w);
    }
    if (e < re) {
        int s0 = csr_src[e];
        float c0 = dinv[s0];
        ushort4 r0 = *(const ushort4*)(xwb + (size_t)s0 * HID + fo);
        accE.x += c0 * bf2f(r0.x);
        accE.y += c0 * bf2f(r0.y);
        accE.z += c0 * bf2f(r0.z);
        accE.w += c0 * bf2f(r0.w);
    }
    float d2 = d * d;
    ushort4 o;
    o.x = f2bf(d * accE.x + d2 * bf2f(sv.x) + b[fo + 0]);
    o.y = f2bf(d * accE.y + d2 * bf2f(sv.y) + b[fo + 1]);
    o.z = f2bf(d * accE.z + d2 * bf2f(sv.z) + b[fo + 2]);
    o.w = f2bf(d * accE.w + d2 * bf2f(sv.w) + b[fo + 3]);
    *(ushort4*)(aggb + (size_t)node * HID + fo) = o;

    // ---- fused BN partial stats -> slot atomics ----
    float v0 = bf2f(o.x), v1 = bf2f(o.y), v2 = bf2f(o.z), v3 = bf2f(o.w);
    int sub = threadIdx.x >> 5;
    rsm[sub][fo + 0] = v0; rsm[sub][fo + 1] = v1;
    rsm[sub][fo + 2] = v2; rsm[sub][fo + 3] = v3;
    rqm[sub][fo + 0] = v0 * v0; rqm[sub][fo + 1] = v1 * v1;
    rqm[sub][fo + 2] = v2 * v2; rqm[sub][fo + 3] = v3 * v3;
    __syncthreads();
    int t = threadIdx.x;
    if (t < 128) {
        float s = 0.f, q = 0.f;
#pragma unroll
        for (int i = 0; i < 8; ++i) { s += rsm[i][t]; q += rqm[i][t]; }
        int slot = blockIdx.x & (NSLOT - 1);
        atomicAdd(&pstatL[slot * 128 + t], s);
        atomicAdd(&pstatL[NSLOT * 128 + slot * 128 + t], q);
    }
}

// ---------------- fused MFMA GEMM: BN+gated-skip (+ optional LDS-resident phase B) ----------------
// phase A: t = BN_relu(A1)@Wa + A2@Wb + biases; z=sigmoid(t); h=z*ox+(1-z)*A2 -> target (hb)
//          epilogue ALSO writes h in-place into its own sm C-slot (1:1, no race).
// phase B (wfC != null): target2 = bf16(h_tile @ Wc). A-frags read from sm (LDS,
//          no global round-trip -- R4's failure mechanism); B read directly from
//          global wfC (32KB, L2-broadcast). acc reused; occupancy unchanged.
__launch_bounds__(256, 4)
__global__ void mgemm_kernel(const unsigned short* __restrict__ A1,
                             const unsigned short* __restrict__ wfA,
                             const unsigned short* __restrict__ A2,
                             const unsigned short* __restrict__ wfB,
                             const float* __restrict__ bias1, const float* __restrict__ bias2,
                             const unsigned short* __restrict__ outx,
                             const float* __restrict__ pstatL,
                             const float* __restrict__ gw, const float* __restrict__ bew,
                             unsigned short* __restrict__ target,
                             const unsigned short* __restrict__ wfC,
                             unsigned short* __restrict__ target2) {
    __shared__ unsigned short sm[128 * CS_STRIDE];   // W-stage / C-stage(h)
    __shared__ float sclS[128], shfS[128];
    int tid = threadIdx.x;
    int lane = tid & 63;
    int wv = tid >> 6;
    int lane15 = lane & 15;
    int q = lane >> 4;
    int m0 = blockIdx.x * 128 + wv * 32;

    if (tid < 128) {
        float s = 0.f, qq = 0.f;
#pragma unroll
        for (int i = 0; i < NSLOT; ++i) {
            s  += pstatL[i * 128 + tid];
            qq += pstatL[NSLOT * 128 + i * 128 + tid];
        }
        float mu = s * (1.0f / NN);
        float var = qq * (1.0f / NN) - mu * mu;
        float sc = gw[tid] * rsqrtf(var + BN_EPS);
        sclS[tid] = sc;
        shfS[tid] = bew[tid] - mu * sc;
    }

    f32x4 acc[2][8];
#pragma unroll
    for (int r = 0; r < 2; ++r)
#pragma unroll
        for (int nt = 0; nt < 8; ++nt)
            acc[r][nt] = (f32x4){0.f, 0.f, 0.f, 0.f};

    bf16x8 zf = {0, 0, 0, 0, 0, 0, 0, 0};
    int row0g = m0 + lane15;
    bool g0 = row0g < NN, g1 = (row0g + 16) < NN;

    for (int p = 0; p < 2; ++p) {
        const unsigned short* A = p ? A2 : A1;
        const unsigned short* wf = p ? wfB : wfA;
        bool bnA = (p == 0);
        __syncthreads();
        for (int g = tid; g < 2048; g += 256) {
            int c = g >> 7, off = (g & 127) << 3;
            *(bf16x8*)&sm[c * LW_STRIDE + off] = *(const bf16x8*)&wf[(c << 10) + off];
        }
        __syncthreads();
        const unsigned short* a0p = A + (size_t)row0g * HID + (q << 3);
        const unsigned short* a1p = a0p + (size_t)16 * HID;
#pragma unroll 4
        for (int k0 = 0; k0 < HID; k0 += 32) {
            bf16x8 af0 = zf, af1 = zf;
            if (g0) af0 = *(const bf16x8*)(a0p + k0);
            if (g1) af1 = *(const bf16x8*)(a1p + k0);
            if (bnA) {
                int kb = k0 + (q << 3);
                float4 s4a = *(const float4*)&sclS[kb];
                float4 s4b = *(const float4*)&sclS[kb + 4];
                float4 h4a = *(const float4*)&shfS[kb];
                float4 h4b = *(const float4*)&shfS[kb + 4];
                float sv[8] = {s4a.x, s4a.y, s4a.z, s4a.w, s4b.x, s4b.y, s4b.z, s4b.w};
                float hv[8] = {h4a.x, h4a.y, h4a.z, h4a.w, h4b.x, h4b.y, h4b.z, h4b.w};
#pragma unroll
                for (int j = 0; j < 8; ++j) {
                    af0[j] = (short)f2bf(fmaxf(bf2f((unsigned short)af0[j]) * sv[j] + hv[j], 0.f));
                    af1[j] = (short)f2bf(fmaxf(bf2f((unsigned short)af1[j]) * sv[j] + hv[j], 0.f));
                }
            }
            const unsigned short* wb = &sm[((k0 >> 3) + q) * LW_STRIDE + (lane15 << 3)];
#pragma unroll
            for (int nt = 0; nt < 8; ++nt) {
                bf16x8 bf = *(const bf16x8*)(wb + nt * 128);
                acc[0][nt] = __builtin_amdgcn_mfma_f32_16x16x32_bf16(af0, bf, acc[0][nt], 0, 0, 0);
                acc[1][nt] = __builtin_amdgcn_mfma_f32_16x16x32_bf16(af1, bf, acc[1][nt], 0, 0, 0);
            }
        }
    }
    __syncthreads();

    {
        float bsum[8];
#pragma unroll
        for (int nt = 0; nt < 8; ++nt)
            bsum[nt] = bias1[nt * 16 + lane15] + bias2[nt * 16 + lane15];
#pragma unroll
        for (int r = 0; r < 2; ++r)
#pragma unroll
            for (int nt = 0; nt < 8; ++nt)
#pragma unroll
                for (int g = 0; g < 4; ++g) {
                    int rr = wv * 32 + r * 16 + q * 4 + g;
                    sm[rr * CS_STRIDE + nt * 16 + lane15] = f2bf(acc[r][nt][g] + bsum[nt]);
                }
    }
    __syncthreads();

#pragma unroll
    for (int i = 0; i < 8; ++i) {
        int rt = (tid >> 4) + i * 16;
        int ch = tid & 15;
        int row = blockIdx.x * 128 + rt;
        if (row >= NN) continue;
        bf16x8 c = *(const bf16x8*)(sm + rt * CS_STRIDE + (ch << 3));
        size_t off = (size_t)row * HID + (ch << 3);
        int cb = ch << 3;
        float4 s4a = *(const float4*)&sclS[cb];
        float4 s4b = *(const float4*)&sclS[cb + 4];
        float4 h4a = *(const float4*)&shfS[cb];
        float4 h4b = *(const float4*)&shfS[cb + 4];
        float sv[8] = {s4a.x, s4a.y, s4a.z, s4a.w, s4b.x, s4b.y, s4b.z, s4b.w};
        float hv[8] = {h4a.x, h4a.y, h4a.z, h4a.w, h4b.x, h4b.y, h4b.z, h4b.w};
        bf16x8 oxv = *(const bf16x8*)(outx + off);
        bf16x8 ixv = *(const bf16x8*)(target + off);
        bf16x8 o;
#pragma unroll
        for (int j = 0; j < 8; ++j) {
            float t = bf2f((unsigned short)c[j]);
            float z = 1.0f / (1.0f + expf(-t));
            float ox = fmaxf(bf2f((unsigned short)oxv[j]) * sv[j] + hv[j], 0.f);
            float h = z * ox + (1.0f - z) * bf2f((unsigned short)ixv[j]);
            o[j] = (short)f2bf(h);
        }
        *(bf16x8*)(target + off) = o;
        // in-place: h replaces t in this thread's own C-slot (for phase B)
        *(bf16x8*)(sm + rt * CS_STRIDE + (ch << 3)) = o;
    }

    if (wfC == nullptr) return;

    // ---------------- phase B: target2 = h_tile(LDS) @ Wc(global) ----------------
    __syncthreads();   // all h slots written
#pragma unroll
    for (int r = 0; r < 2; ++r)
#pragma unroll
        for (int nt = 0; nt < 8; ++nt)
            acc[r][nt] = (f32x4){0.f, 0.f, 0.f, 0.f};
    {
        int lrow = wv * 32 + lane15;
#pragma unroll
        for (int k0 = 0; k0 < HID; k0 += 32) {
            bf16x8 af0 = *(const bf16x8*)&sm[lrow * CS_STRIDE + k0 + (q << 3)];
            bf16x8 af1 = *(const bf16x8*)&sm[(lrow + 16) * CS_STRIDE + k0 + (q << 3)];
            int c = (k0 >> 3) + q;
            const unsigned short* wb = wfC + (c << 10) + (lane15 << 3);
#pragma unroll
            for (int nt = 0; nt < 8; ++nt) {
                bf16x8 bf = *(const bf16x8*)(wb + nt * 128);
                acc[0][nt] = __builtin_amdgcn_mfma_f32_16x16x32_bf16(af0, bf, acc[0][nt], 0, 0, 0);
                acc[1][nt] = __builtin_amdgcn_mfma_f32_16x16x32_bf16(af1, bf, acc[1][nt], 0, 0, 0);
            }
        }
    }
    __syncthreads();
#pragma unroll
    for (int r = 0; r < 2; ++r)
#pragma unroll
        for (int nt = 0; nt < 8; ++nt)
#pragma unroll
            for (int g = 0; g < 4; ++g) {
                int rr = wv * 32 + r * 16 + q * 4 + g;
                sm[rr * CS_STRIDE + nt * 16 + lane15] = f2bf(acc[r][nt][g]);
            }
    __syncthreads();
#pragma unroll
    for (int i = 0; i < 8; ++i) {
        int rt = (tid >> 4) + i * 16;
        int ch = tid & 15;
        int row = blockIdx.x * 128 + rt;
        if (row >= NN) continue;
        bf16x8 c = *(const bf16x8*)(sm + rt * CS_STRIDE + (ch << 3));
        *(bf16x8*)(target2 + (size_t)row * HID + (ch << 3)) = c;
    }
}

// ---------------- MLP head with fused vectorized pool3 ----------------
__global__ void head_kernel(const float* __restrict__ pool1, const float* __restrict__ pool2,
                            const unsigned short* __restrict__ h3,
                            const int* __restrict__ gstart,
                            const float* __restrict__ eF,
                            const float* __restrict__ fc1W, const float* __restrict__ fc1b,
                            const float* __restrict__ fc3W, const float* __restrict__ fc3b,
                            float* __restrict__ out) {
    __shared__ float hg[3 * HID + EXD];
    __shared__ float hh[HID];
    __shared__ float red[8][128];
    int g = blockIdx.x, t = threadIdx.x;
    int lane = t & 31, sub = t >> 5;
    int s = gstart[g], e = gstart[g + 1];
    float4 acc = make_float4(0.f, 0.f, 0.f, 0.f);
    for (int r = s + sub; r < e; r += 8) {
        ushort4 v = *(const ushort4*)(h3 + (size_t)r * HID + (lane << 2));
        acc.x += bf2f(v.x); acc.y += bf2f(v.y);
        acc.z += bf2f(v.z); acc.w += bf2f(v.w);
    }
    *(float4*)&red[sub][lane << 2] = acc;
    if (t < 128) {
        hg[t]       = pool1[(size_t)g * HID + t];
        hg[HID + t] = pool2[(size_t)g * HID + t];
    } else if (t < 128 + EXD) {
        hg[3 * HID + (t - 128)] = eF[(size_t)g * EXD + (t - 128)];
    }
    __syncthreads();
    if (t < 128) {
        float a = 0.f;
#pragma unroll
        for (int i = 0; i < 8; ++i) a += red[i][t];
        hg[2 * HID + t] = a / (float)max(e - s, 1);
    }
    __syncthreads();
    if (t < 128) {
        float a = fc1b[t];
        for (int k = 0; k < 3 * HID + EXD; ++k) a += hg[k] * fc1W[(size_t)k * HID + t];
        hh[t] = fmaxf(a, 0.f);
    }
    __syncthreads();
    if (t < OUTD) {
        float a2 = fc3b[t];
        for (int k = 0; k < HID; ++k) a2 += hh[k] * fc3W[(size_t)k * OUTD + t];
        out[(size_t)g * OUTD + t] = a2;
    }
}

// ---------------- launch ----------------

extern "C" void kernel_launch(void* const* d_in, const int* in_sizes, int n_in,
                              void* d_out, int out_size, void* d_ws, size_t ws_size,
                              hipStream_t stream) {
    const float* x      = (const float*)d_in[0];
    const float* eF     = (const float*)d_in[1];
    const int*   ei     = (const int*)d_in[2];
    const int*   batch  = (const int*)d_in[3];
    const int* src = ei;
    const int* dst = ei + NE;

    const float* W1 = (const float*)d_in[4];  const float* b1 = (const float*)d_in[5];
    const float* W2 = (const float*)d_in[6];  const float* b2 = (const float*)d_in[7];
    const float* W3 = (const float*)d_in[8];  const float* b3 = (const float*)d_in[9];
    const float* g1 = (const float*)d_in[10]; const float* be1 = (const float*)d_in[11];
    const float* g2 = (const float*)d_in[12]; const float* be2 = (const float*)d_in[13];
    const float* g3 = (const float*)d_in[14]; const float* be3 = (const float*)d_in[15];
    const float* s1_Wp = (const float*)d_in[16];
    const float* s1_Wi = (const float*)d_in[17]; const float* s1_bi = (const float*)d_in[18];
    const float* s1_Wo = (const float*)d_in[19]; const float* s1_bo = (const float*)d_in[20];
    const float* s2_Wi = (const float*)d_in[21]; const float* s2_bi = (const float*)d_in[22];
    const float* s2_Wo = (const float*)d_in[23]; const float* s2_bo = (const float*)d_in[24];
    const float* s3_Wi = (const float*)d_in[25]; const float* s3_bi = (const float*)d_in[26];
    const float* s3_Wo = (const float*)d_in[27]; const float* s3_bo = (const float*)d_in[28];
    const float* fc1W = (const float*)d_in[29]; const float* fc1b = (const float*)d_in[30];
    const float* fc3W = (const float*)d_in[31]; const float* fc3b = (const float*)d_in[32];

    size_t S = (size_t)NN * HID;
    unsigned short* xwb  = (unsigned short*)d_ws;          // NN*HID
    unsigned short* xslot = xwb + S;                       // freed xb slot -> transients
    unsigned short* hb   = xslot + (size_t)NN * IN_DIM;    // NN*HID
    unsigned short* aggb = hb + S;                         // NN*HID
    unsigned short* wfb  = aggb + S;                       // 8*16384
    float* dinv = (float*)(wfb + 10 * 16384);              // NN
    int*   rs_raw = (int*)(dinv + NN);                     // NN+1
    int*   csr_src   = rs_raw + NN + 1;                    // NE
    int*   gstart    = csr_src + NE;                       // NG+1
    float* pstat = (float*)(gstart + NG + 1);              // 3 * PSTAT_L floats
    float* pools = pstat + 3 * PSTAT_L;                    // 2*NG*HID used
    // transients in the freed xb slot:
    int* deg   = (int*)xslot;                              // NN ints
    unsigned char* epos = (unsigned char*)(deg + NN);      // NE bytes
    int* bsums = (int*)(epos + NE);                        // NBLK ints
    int* row_fin = bsums + 512;                            // NN+1 ints

    const int TB = 256;
    const int NB  = (NN + TB - 1) / TB;

    unsigned short* wfS1i  = wfb + 0 * 16384;
    unsigned short* wfS1o  = wfb + 1 * 16384;
    unsigned short* wfW2   = wfb + 2 * 16384;
    unsigned short* wfS2i  = wfb + 3 * 16384;
    unsigned short* wfS2o  = wfb + 4 * 16384;
    unsigned short* wfW3   = wfb + 5 * 16384;
    unsigned short* wfS3i  = wfb + 6 * 16384;
    unsigned short* wfS3o  = wfb + 7 * 16384;

    WPack wp;
    wp.w[0] = s1_Wi; wp.K[0] = HID;
    wp.w[1] = s1_Wo; wp.K[1] = HID;
    wp.w[2] = W2;    wp.K[2] = HID;
    wp.w[3] = s2_Wi; wp.K[3] = HID;
    wp.w[4] = s2_Wo; wp.K[4] = HID;
    wp.w[5] = W3;    wp.K[5] = HID;
    wp.w[6] = s3_Wi; wp.K[6] = HID;
    wp.w[7] = s3_Wo; wp.K[7] = HID;
    wp.w[8] = W2;    wp.K[8] = 0;
    wp.w[9] = W2;    wp.K[9] = 0;

    float* pst1 = pstat;
    float* pst2 = pstat + PSTAT_L;
    float* pst3 = pstat + 2 * PSTAT_L;

    // ---- mega1: degpos atomics || layer-1 dual GEMM || wprep || gstart ----
    hipMemsetAsync(deg, 0, NN * sizeof(int), stream);
    mega1_kernel<<<MEGA_TOT, TB, 0, stream>>>(src, dst, deg, epos, batch, gstart,
                                              x, W1, s1_Wp, wp, wfb, xwb, hb);
    scan1_kernel<<<NBLK, SCAN_B, 0, stream>>>(deg, rs_raw, bsums, dinv, pstat);
    fill_kernel<<<FILL_B + NB, TB, 0, stream>>>(src, dst, rs_raw, bsums, epos,
                                                csr_src, row_fin);

    // ---- layer 1: gather -> fused mode1+phaseB (h1 -> hb; xwb = h1 @ W2) ----
    gather_kernel<<<AGB, TB, 0, stream>>>(row_fin, csr_src, xwb, dinv, b1, aggb, pst1,
                                          nullptr, nullptr, nullptr);
    mgemm_kernel<<<GB2K, TB, 0, stream>>>(aggb, wfS1o, hb, wfS1i,
                                          s1_bo, s1_bi, aggb, pst1, g1, be1, hb,
                                          wfW2, xwb);

    // ---- layer 2 (gather carries pool1 over h1) ----
    gather_kernel<<<AGB + NG, TB, 0, stream>>>(row_fin, csr_src, xwb, dinv, b2, aggb, pst2,
                                               hb, gstart, pools);
    mgemm_kernel<<<GB2K, TB, 0, stream>>>(aggb, wfS2o, hb, wfS2i,
                                          s2_bo, s2_bi, aggb, pst2, g2, be2, hb,
                                          wfW3, xwb);

    // ---- layer 3 (gather carries pool2 over h2) ----
    gather_kernel<<<AGB + NG, TB, 0, stream>>>(row_fin, csr_src, xwb, dinv, b3, aggb, pst3,
                                               hb, gstart, pools + (size_t)NG * HID);
    mgemm_kernel<<<GB2K, TB, 0, stream>>>(aggb, wfS3o, hb, wfS3i,
                                          s3_bo, s3_bi, aggb, pst3, g3, be3, hb,
                                          nullptr, nullptr);

    // ---- head (vectorized pool3 fused) ----
    head_kernel<<<NG, TB, 0, stream>>>(pools, pools + (size_t)NG * HID,
                                       hb, gstart, eF,
                                       fc1W, fc1b, fc3W, fc3b, (float*)d_out);
}